// Round 8
// baseline (334.586 us; speedup 1.0000x reference)
//
#include <hip/hip_runtime.h>
#include <hip/hip_bf16.h>
#include <math.h>

#define NH 8
#define HD 32
#define EDIM 256
#define NL 4
#define NP 20
#define NR 4
#define SEQ 1024
#define BATCH 4
#define TOTAL 20197
#define OFF_SCALE 4.0f

#define M_ENC (BATCH * TOTAL)   // 80788
#define KDIM 256
#define LDSW 40                 // padded LDS row stride (bf16): 80B -> 2-way banks only

typedef short bf16x8 __attribute__((ext_vector_type(8)));
typedef float f32x4  __attribute__((ext_vector_type(4)));

__device__ __forceinline__ unsigned short f32_to_bf16_rne(float f) {
    unsigned u = __float_as_uint(f);
    return (unsigned short)((u + 0x7fffu + ((u >> 16) & 1u)) >> 16);
}

// ---------------------------------------------------------------------------
// f32 -> bf16 cast (RNE). Used only for the small weight matrices now.
// ---------------------------------------------------------------------------
__global__ __launch_bounds__(256) void cast_f32_bf16_kernel(
    const float* __restrict__ src, unsigned short* __restrict__ dst,
    long n)
{
    long i = (long)blockIdx.x * blockDim.x + threadIdx.x;
    long stride = (long)gridDim.x * blockDim.x;
    for (long e = i * 8; e < n; e += stride * 8) {
        float4 a = *reinterpret_cast<const float4*>(src + e);
        float4 b = *reinterpret_cast<const float4*>(src + e + 4);
        float f[8] = {a.x, a.y, a.z, a.w, b.x, b.y, b.z, b.w};
        unsigned short o[8];
        #pragma unroll
        for (int j = 0; j < 8; ++j) o[j] = f32_to_bf16_rne(f[j]);
        *reinterpret_cast<uint4*>(dst + e) = *reinterpret_cast<const uint4*>(o);
    }
}

// ---------------------------------------------------------------------------
// MFMA GEMM with fused f32->bf16 A-staging:
//   C[m][n] = sum_k A_f32[m][k]*W_bf16[n][k] + bias[n];  f32 out.
// A: (>=M_real, 256) f32 row-major, rows >= M_real are read-guarded to 0.
// W: (N, 256) bf16 row-major. Grid: (ceil(M/128), N/128). 128x128 tile,
// BK=32, 4 waves; LDS rows padded to 40 bf16 (2-way banks only).
// Numerics identical to cast-then-GEMM (same RNE).
// ---------------------------------------------------------------------------
__global__ __launch_bounds__(256) void gemm_mfma_f32a_kernel(
    const float* __restrict__ A,
    const unsigned short* __restrict__ W,
    const float* __restrict__ bias,
    float* __restrict__ C,
    int M_real, int N)
{
    __shared__ __align__(16) unsigned short As[128 * LDSW];
    __shared__ __align__(16) unsigned short Ws[128 * LDSW];

    const int tid  = threadIdx.x;
    const int m0   = blockIdx.x * 128;
    const int n0   = blockIdx.y * 128;
    const int wave = tid >> 6;
    const int lane = tid & 63;
    const int wr   = wave >> 1;
    const int wc   = wave & 1;
    const int lrow = lane & 15;
    const int kg   = lane >> 4;

    f32x4 acc[4][4] = {};

    for (int k0 = 0; k0 < KDIM; k0 += 32) {
        // ---- A: 128 rows x 32 f32, convert->bf16, stage. 1024 float4 slots.
        #pragma unroll
        for (int p = 0; p < 4; ++p) {
            int s   = tid + p * 256;      // 0..1023
            int row = s >> 3;             // 0..127
            int sl  = s & 7;              // float4 slot within the 32-k strip
            int gm  = m0 + row;
            float4 v = make_float4(0.f, 0.f, 0.f, 0.f);
            if (gm < M_real)
                v = *reinterpret_cast<const float4*>(&A[(size_t)gm * KDIM + k0 + sl * 4]);
            unsigned short o[4] = {
                f32_to_bf16_rne(v.x), f32_to_bf16_rne(v.y),
                f32_to_bf16_rne(v.z), f32_to_bf16_rne(v.w)};
            *reinterpret_cast<uint2*>(&As[row * LDSW + sl * 4]) =
                *reinterpret_cast<const uint2*>(o);
        }
        // ---- W: 128 rows x 32 bf16 (already bf16), 512 uint4 slots.
        #pragma unroll
        for (int it = 0; it < 2; ++it) {
            int s   = tid + it * 256;
            int row = s >> 2;
            int ks  = s & 3;
            uint4 vw = *reinterpret_cast<const uint4*>(
                W + (size_t)(n0 + row) * KDIM + k0 + ks * 8);
            *reinterpret_cast<uint4*>(&Ws[row * LDSW + ks * 8]) = vw;
        }
        __syncthreads();

        bf16x8 af[4], bfr[4];
        #pragma unroll
        for (int mi = 0; mi < 4; ++mi)
            af[mi] = *reinterpret_cast<const bf16x8*>(
                &As[(wr * 64 + mi * 16 + lrow) * LDSW + kg * 8]);
        #pragma unroll
        for (int nj = 0; nj < 4; ++nj)
            bfr[nj] = *reinterpret_cast<const bf16x8*>(
                &Ws[(wc * 64 + nj * 16 + lrow) * LDSW + kg * 8]);
        #pragma unroll
        for (int mi = 0; mi < 4; ++mi)
            #pragma unroll
            for (int nj = 0; nj < 4; ++nj)
                acc[mi][nj] = __builtin_amdgcn_mfma_f32_16x16x32_bf16(
                    af[mi], bfr[nj], acc[mi][nj], 0, 0, 0);
        __syncthreads();
    }

    #pragma unroll
    for (int mi = 0; mi < 4; ++mi) {
        #pragma unroll
        for (int nj = 0; nj < 4; ++nj) {
            int row_base = m0 + wr * 64 + mi * 16 + kg * 4;
            int col      = n0 + wc * 64 + nj * 16 + lrow;
            float bv = bias ? bias[col] : 0.f;
            #pragma unroll
            for (int r = 0; r < 4; ++r) {
                int row = row_base + r;
                if (row < M_real)
                    C[(size_t)row * N + col] = acc[mi][nj][r] + bv;
            }
        }
    }
}

// ---------------------------------------------------------------------------
// Generic f32 GEMM (ref proj + out proj): C = A @ W^T + bias
// ---------------------------------------------------------------------------
__global__ __launch_bounds__(256) void gemm_atb_kernel(
    const float* __restrict__ A, const float* __restrict__ W,
    const float* __restrict__ bias, float* __restrict__ C,
    int M, int N, int K)
{
    __shared__ float As[16][64];
    __shared__ float Wt[16][64];

    const int tid = threadIdx.x;
    const int m0 = blockIdx.x * 64;
    const int n0 = blockIdx.y * 64;
    const int tx = tid & 15;
    const int ty = tid >> 4;
    const int lr = tid >> 2;
    const int lk = (tid & 3) << 2;

    const int am = m0 + lr;
    const int wn = n0 + lr;

    float acc[4][4] = {};

    for (int k0 = 0; k0 < K; k0 += 16) {
        float4 av = make_float4(0.f, 0.f, 0.f, 0.f);
        float4 wv = make_float4(0.f, 0.f, 0.f, 0.f);
        if (am < M) av = *reinterpret_cast<const float4*>(&A[(size_t)am * K + k0 + lk]);
        if (wn < N) wv = *reinterpret_cast<const float4*>(&W[(size_t)wn * K + k0 + lk]);
        As[lk + 0][lr] = av.x; As[lk + 1][lr] = av.y;
        As[lk + 2][lr] = av.z; As[lk + 3][lr] = av.w;
        Wt[lk + 0][lr] = wv.x; Wt[lk + 1][lr] = wv.y;
        Wt[lk + 2][lr] = wv.z; Wt[lk + 3][lr] = wv.w;
        __syncthreads();

        #pragma unroll
        for (int k = 0; k < 16; ++k) {
            float a[4], b[4];
            #pragma unroll
            for (int i = 0; i < 4; ++i) a[i] = As[k][ty * 4 + i];
            #pragma unroll
            for (int j = 0; j < 4; ++j) b[j] = Wt[k][tx * 4 + j];
            #pragma unroll
            for (int i = 0; i < 4; ++i)
                #pragma unroll
                for (int j = 0; j < 4; ++j)
                    acc[i][j] += a[i] * b[j];
        }
        __syncthreads();
    }

    #pragma unroll
    for (int i = 0; i < 4; ++i) {
        int m = m0 + ty * 4 + i;
        if (m >= M) continue;
        #pragma unroll
        for (int j = 0; j < 4; ++j) {
            int n = n0 + tx * 4 + j;
            if (n >= N) continue;
            float v = acc[i][j];
            if (bias) v += bias[n];
            C[(size_t)m * N + n] = v;
        }
    }
}

// ---------------------------------------------------------------------------
// Deformable sampling, wave-parallel (unchanged from round 6's verified run).
// ---------------------------------------------------------------------------
__global__ __launch_bounds__(256) void deform_sample_kernel(
    const float* __restrict__ values,    // (B, TOTAL, NH, HD)
    const float* __restrict__ proj_off,  // (B*SEQ, 1280)
    const float* __restrict__ proj_attn, // (B*SEQ, 640)
    const float* __restrict__ proj_ref,  // (B*SEQ, 32)
    const float* __restrict__ def_refs,  // (NR, 2)
    float* __restrict__ out)             // (B*SEQ, 256)
{
    const int row = blockIdx.x;
    const int b   = row >> 10;           // SEQ = 1024
    const int tid = threadIdx.x;

    __shared__ float  attn_s[NH * NL * NP];   // 640 f32
    __shared__ float  anchors[NH][2];
    __shared__ unsigned int sidx[NH * NL * NP][2];  // 4 x u16 packed
    __shared__ float4 wcor[NH * NL * NP];           // 4 corner weights

    // ---- Phase A ----
    if (tid >= 96) {            // 160 threads: vector-load attn logits
        int i = tid - 96;
        reinterpret_cast<float4*>(attn_s)[i] =
            reinterpret_cast<const float4*>(proj_attn + (size_t)row * 640)[i];
    } else if (tid < NH) {      // 8 threads: anchors
        const int h = tid;
        float rv[NR];
        float rmax = -1e30f;
        #pragma unroll
        for (int r = 0; r < NR; ++r) {
            rv[r] = proj_ref[(size_t)row * (NH * NR) + h * NR + r];
            rmax = fmaxf(rmax, rv[r]);
        }
        float rsum = 0.f;
        #pragma unroll
        for (int r = 0; r < NR; ++r) { rv[r] = __expf(rv[r] - rmax); rsum += rv[r]; }
        float ax = 0.f, ay = 0.f;
        #pragma unroll
        for (int r = 0; r < NR; ++r) {
            float pr = rv[r] / rsum;
            float sx = 1.f / (1.f + __expf(-def_refs[r * 2 + 0]));
            float sy = 1.f / (1.f + __expf(-def_refs[r * 2 + 1]));
            ax += pr * sx; ay += pr * sy;
        }
        anchors[h][0] = ax; anchors[h][1] = ay;
    }
    __syncthreads();

    // ---- Phase A2: per-head softmax over 80, 32 lanes per head ----
    {
        const int g = tid >> 5;   // head
        const int l = tid & 31;
        float v0 = attn_s[g * 80 + l];
        float v1 = attn_s[g * 80 + 32 + l];
        float v2 = (l < 16) ? attn_s[g * 80 + 64 + l] : -1e30f;
        float m = fmaxf(fmaxf(v0, v1), v2);
        #pragma unroll
        for (int d = 16; d >= 1; d >>= 1) m = fmaxf(m, __shfl_xor(m, d, 64));
        float e0 = __expf(v0 - m), e1 = __expf(v1 - m);
        float e2 = (l < 16) ? __expf(v2 - m) : 0.f;
        float s = e0 + e1 + e2;
        #pragma unroll
        for (int d = 16; d >= 1; d >>= 1) s += __shfl_xor(s, d, 64);
        float inv = 1.f / s;
        __syncthreads();   // all reads of raw logits done before overwrite
        attn_s[g * 80 + l]      = e0 * inv;
        attn_s[g * 80 + 32 + l] = e1 * inv;
        if (l < 16) attn_s[g * 80 + 64 + l] = e2 * inv;
    }
    __syncthreads();

    // ---- Phase B: sample locations -> packed indices + folded weights ----
    const int lhh[NL] = {100, 50, 25, 13};
    const int lww[NL] = {152, 76, 38, 19};
    const int lst[NL] = {0, 15200, 19000, 19950};

    for (int e = tid; e < NH * NL * NP; e += 256) {
        int h = e / 80;
        int rem = e - h * 80;
        int l = rem / 20;
        const float2 o = *reinterpret_cast<const float2*>(
            proj_off + (size_t)row * 1280 + e * 2);
        float offx = tanhf(o.x);
        float offy = tanhf(o.y);
        int ww = lww[l], hh = lhh[l];
        float locx = fminf(fmaxf(anchors[h][0] + offx * (OFF_SCALE / (float)ww), 0.f), 1.f);
        float locy = fminf(fmaxf(anchors[h][1] + offy * (OFF_SCALE / (float)hh), 0.f), 1.f);
        float xx = locx * (float)ww - 0.5f;
        float yy = locy * (float)hh - 0.5f;
        float x0f = floorf(xx), y0f = floorf(yy);
        int x0 = (int)x0f, y0 = (int)y0f;
        float wx = xx - x0f, wy = yy - y0f;
        float wa = attn_s[e];

        float bx0 = (x0 >= 0)      ? 1.f : 0.f;
        float bx1 = (x0 < ww - 1)  ? 1.f : 0.f;
        float by0 = (y0 >= 0)      ? 1.f : 0.f;
        float by1 = (y0 < hh - 1)  ? 1.f : 0.f;
        int xc0 = max(x0, 0), xc1 = min(x0 + 1, ww - 1);
        int yc0 = max(y0, 0), yc1 = min(y0 + 1, hh - 1);
        unsigned int i00 = (unsigned int)(lst[l] + yc0 * ww + xc0);
        unsigned int i10 = (unsigned int)(lst[l] + yc0 * ww + xc1);
        unsigned int i01 = (unsigned int)(lst[l] + yc1 * ww + xc0);
        unsigned int i11 = (unsigned int)(lst[l] + yc1 * ww + xc1);

        float4 w;
        w.x = wa * (1.f - wx) * (1.f - wy) * bx0 * by0;
        w.y = wa * wx * (1.f - wy) * bx1 * by0;
        w.z = wa * (1.f - wx) * wy * bx0 * by1;
        w.w = wa * wx * wy * bx1 * by1;

        sidx[e][0] = i00 | (i10 << 16);
        sidx[e][1] = i01 | (i11 << 16);
        wcor[e] = w;
    }
    __syncthreads();

    // ---- Phase C: gather + accumulate ----
    const int h = tid >> 5;
    const int c = tid & 31;
    const float* vb = values + (size_t)b * TOTAL * 256 + h * 32 + c;
    float acc = 0.f;
    #pragma unroll 4
    for (int i = 0; i < 80; ++i) {
        int e = h * 80 + i;
        unsigned int p0 = sidx[e][0];
        unsigned int p1 = sidx[e][1];
        float4 w = wcor[e];
        float v00 = vb[(size_t)(p0 & 0xffffu) * 256];
        float v10 = vb[(size_t)(p0 >> 16) * 256];
        float v01 = vb[(size_t)(p1 & 0xffffu) * 256];
        float v11 = vb[(size_t)(p1 >> 16) * 256];
        acc += w.x * v00 + w.y * v10 + w.z * v01 + w.w * v11;
    }
    out[(size_t)row * 256 + h * 32 + c] = acc;
}

// ---------------------------------------------------------------------------
extern "C" void kernel_launch(void* const* d_in, const int* in_sizes, int n_in,
                              void* d_out, int out_size, void* d_ws, size_t ws_size,
                              hipStream_t stream)
{
    const float* x        = (const float*)d_in[0];
    const float* enc      = (const float*)d_in[1];
    const float* v_w      = (const float*)d_in[2];
    const float* out_w    = (const float*)d_in[3];
    const float* off_w    = (const float*)d_in[4];
    const float* off_b    = (const float*)d_in[5];
    const float* attn_w   = (const float*)d_in[6];
    const float* attn_b   = (const float*)d_in[7];
    const float* ref_w    = (const float*)d_in[8];
    const float* ref_b    = (const float*)d_in[9];
    const float* def_refs = (const float*)d_in[10];
    float* out = (float*)d_out;

    const int M_Q    = BATCH * SEQ;       // 4096
    const int N_OFF  = NH * NL * NP * 2;  // 1280
    const int N_ATTN = NH * NL * NP;      // 640
    const int N_REF  = NH * NR;           // 32

    // ---- workspace layout (~120 MB, no aliasing) ----
    float* ws = (float*)d_ws;
    float* values    = ws;                                    // 82.7 MB
    float* proj_off  = values    + (size_t)M_ENC * EDIM;      // 21.0 MB
    float* proj_attn = proj_off  + (size_t)M_Q * N_OFF;       // 10.5 MB
    float* proj_ref  = proj_attn + (size_t)M_Q * N_ATTN;      //  0.5 MB
    float* attn_out  = proj_ref  + (size_t)M_Q * N_REF;       //  4.2 MB
    unsigned short* vw_bf16    = (unsigned short*)(attn_out + (size_t)M_Q * EDIM);
    unsigned short* offw_bf16  = vw_bf16   + (size_t)EDIM * KDIM;
    unsigned short* attnw_bf16 = offw_bf16 + (size_t)N_OFF * KDIM;

    dim3 blk(256);

    // 1) weight casts (small)
    cast_f32_bf16_kernel<<<dim3(32), blk, 0, stream>>>(v_w, vw_bf16, (long)EDIM * KDIM);
    cast_f32_bf16_kernel<<<dim3(160), blk, 0, stream>>>(off_w, offw_bf16, (long)N_OFF * KDIM);
    cast_f32_bf16_kernel<<<dim3(80), blk, 0, stream>>>(attn_w, attnw_bf16, (long)N_ATTN * KDIM);

    // 2) values = enc @ v_w^T (fused f32->bf16 staging MFMA)
    gemm_mfma_f32a_kernel<<<dim3((M_ENC + 127) / 128, EDIM / 128), blk, 0, stream>>>(
        enc, vw_bf16, nullptr, values, M_ENC, EDIM);

    // 3) projections: off + attn via fused MFMA (bias fused), ref via f32
    gemm_mfma_f32a_kernel<<<dim3(M_Q / 128, N_OFF / 128), blk, 0, stream>>>(
        x, offw_bf16, off_b, proj_off, M_Q, N_OFF);
    gemm_mfma_f32a_kernel<<<dim3(M_Q / 128, N_ATTN / 128), blk, 0, stream>>>(
        x, attnw_bf16, attn_b, proj_attn, M_Q, N_ATTN);
    gemm_atb_kernel<<<dim3(M_Q / 64, 1), blk, 0, stream>>>(
        x, ref_w, ref_b, proj_ref, M_Q, N_REF, EDIM);

    // 4) deformable sampling (wave-parallel)
    deform_sample_kernel<<<dim3(M_Q), blk, 0, stream>>>(
        values, proj_off, proj_attn, proj_ref, def_refs, attn_out);

    // 5) out = attn_out @ out_w^T (f32)
    gemm_atb_kernel<<<dim3(M_Q / 64, EDIM / 64), blk, 0, stream>>>(
        attn_out, out_w, nullptr, out, M_Q, EDIM, EDIM);
}

// Round 9
// 329.630 us; speedup vs baseline: 1.0150x; 1.0150x over previous
//
#include <hip/hip_runtime.h>
#include <hip/hip_bf16.h>
#include <math.h>

#define NH 8
#define HD 32
#define EDIM 256
#define NL 4
#define NP 20
#define NR 4
#define SEQ 1024
#define BATCH 4
#define TOTAL 20197
#define OFF_SCALE 4.0f

#define M_ENC (BATCH * TOTAL)   // 80788
#define KDIM 256
#define LDSW 40                 // padded LDS row stride (bf16): 80B

typedef short bf16x8 __attribute__((ext_vector_type(8)));
typedef float f32x4  __attribute__((ext_vector_type(4)));

__device__ __forceinline__ unsigned short f32_to_bf16_rne(float f) {
    unsigned u = __float_as_uint(f);
    return (unsigned short)((u + 0x7fffu + ((u >> 16) & 1u)) >> 16);
}

// ---------------------------------------------------------------------------
// Fused triple f32->bf16 cast (weights): one dispatch instead of three.
// All sizes divisible by 8.
// ---------------------------------------------------------------------------
__global__ __launch_bounds__(256) void cast3_kernel(
    const float* __restrict__ s0, unsigned short* __restrict__ d0, long n0,
    const float* __restrict__ s1, unsigned short* __restrict__ d1, long n1,
    const float* __restrict__ s2, unsigned short* __restrict__ d2, long n2)
{
    long c0 = n0 >> 3, c1 = n1 >> 3, c2 = n2 >> 3;
    long total = c0 + c1 + c2;
    long gid = (long)blockIdx.x * blockDim.x + threadIdx.x;
    long stride = (long)gridDim.x * blockDim.x;
    for (long i = gid; i < total; i += stride) {
        const float* s; unsigned short* d; long e;
        if (i < c0)            { s = s0; d = d0; e = i * 8; }
        else if (i < c0 + c1)  { s = s1; d = d1; e = (i - c0) * 8; }
        else                   { s = s2; d = d2; e = (i - c0 - c1) * 8; }
        float4 a = *reinterpret_cast<const float4*>(s + e);
        float4 b = *reinterpret_cast<const float4*>(s + e + 4);
        float f[8] = {a.x, a.y, a.z, a.w, b.x, b.y, b.z, b.w};
        unsigned short o[8];
        #pragma unroll
        for (int j = 0; j < 8; ++j) o[j] = f32_to_bf16_rne(f[j]);
        *reinterpret_cast<uint4*>(d + e) = *reinterpret_cast<const uint4*>(o);
    }
}

// ---------------------------------------------------------------------------
// Pipelined MFMA GEMM with fused f32->bf16 A-staging (2-stage, reg-staged
// double buffer):  C[m][n] = sum_k A_f32[m][k]*W_bf16[n][k] + bias[n].
// Per K-step: issue global loads for t+1 -> compute buf[t&1] -> convert+
// ds_write buf[(t+1)&1] -> ONE barrier. Loads stay in flight across compute.
// LDS 2x(A+W) = 40KB -> 4 blocks/CU. Numerics identical to cast-then-GEMM.
// ---------------------------------------------------------------------------
__global__ __launch_bounds__(256) void gemm_mfma_f32a_kernel(
    const float* __restrict__ A,
    const unsigned short* __restrict__ W,
    const float* __restrict__ bias,
    float* __restrict__ C,
    int M_real, int N)
{
    __shared__ __align__(16) unsigned short As[2][128 * LDSW];
    __shared__ __align__(16) unsigned short Ws[2][128 * LDSW];

    const int tid  = threadIdx.x;
    const int m0   = blockIdx.x * 128;
    const int n0   = blockIdx.y * 128;
    const int wave = tid >> 6;
    const int lane = tid & 63;
    const int wr   = wave >> 1;
    const int wc   = wave & 1;
    const int lrow = lane & 15;
    const int kg   = lane >> 4;

    const int arow = tid >> 3;   // 0..31  (+32 per p)
    const int asl  = tid & 7;    // float4 slot in 32-k strip
    const int wrow = tid >> 2;   // 0..63  (+64 per it)
    const int wks  = tid & 3;    // uint4 slot

    f32x4  acc[4][4] = {};
    float4 areg[4];
    uint4  wreg[2];

    auto LOADT = [&](int t) {
        const int k0 = t * 32;
        #pragma unroll
        for (int p = 0; p < 4; ++p) {
            int gm = m0 + arow + 32 * p;
            float4 v = make_float4(0.f, 0.f, 0.f, 0.f);
            if (gm < M_real)
                v = *reinterpret_cast<const float4*>(
                    &A[(size_t)gm * KDIM + k0 + asl * 4]);
            areg[p] = v;
        }
        #pragma unroll
        for (int it = 0; it < 2; ++it)
            wreg[it] = *reinterpret_cast<const uint4*>(
                &W[(size_t)(n0 + wrow + 64 * it) * KDIM + k0 + wks * 8]);
    };
    auto STORE = [&](int b) {
        #pragma unroll
        for (int p = 0; p < 4; ++p) {
            unsigned short o[4] = {
                f32_to_bf16_rne(areg[p].x), f32_to_bf16_rne(areg[p].y),
                f32_to_bf16_rne(areg[p].z), f32_to_bf16_rne(areg[p].w)};
            *reinterpret_cast<uint2*>(&As[b][(arow + 32 * p) * LDSW + asl * 4]) =
                *reinterpret_cast<const uint2*>(o);
        }
        #pragma unroll
        for (int it = 0; it < 2; ++it)
            *reinterpret_cast<uint4*>(&Ws[b][(wrow + 64 * it) * LDSW + wks * 8]) =
                wreg[it];
    };
    auto COMPUTE = [&](int b) {
        bf16x8 af[4], bfr[4];
        #pragma unroll
        for (int mi = 0; mi < 4; ++mi)
            af[mi] = *reinterpret_cast<const bf16x8*>(
                &As[b][(wr * 64 + mi * 16 + lrow) * LDSW + kg * 8]);
        #pragma unroll
        for (int nj = 0; nj < 4; ++nj)
            bfr[nj] = *reinterpret_cast<const bf16x8*>(
                &Ws[b][(wc * 64 + nj * 16 + lrow) * LDSW + kg * 8]);
        #pragma unroll
        for (int mi = 0; mi < 4; ++mi)
            #pragma unroll
            for (int nj = 0; nj < 4; ++nj)
                acc[mi][nj] = __builtin_amdgcn_mfma_f32_16x16x32_bf16(
                    af[mi], bfr[nj], acc[mi][nj], 0, 0, 0);
    };

    LOADT(0);
    STORE(0);
    __syncthreads();
    #pragma unroll
    for (int t = 0; t < 8; ++t) {
        if (t < 7) LOADT(t + 1);          // in flight across COMPUTE
        COMPUTE(t & 1);
        if (t < 7) {
            STORE((t + 1) & 1);           // vmcnt-waits on areg/wreg here
            __syncthreads();              // one barrier per K-step
        }
    }

    #pragma unroll
    for (int mi = 0; mi < 4; ++mi) {
        #pragma unroll
        for (int nj = 0; nj < 4; ++nj) {
            int row_base = m0 + wr * 64 + mi * 16 + kg * 4;
            int col      = n0 + wc * 64 + nj * 16 + lrow;
            float bv = bias ? bias[col] : 0.f;
            #pragma unroll
            for (int r = 0; r < 4; ++r) {
                int row = row_base + r;
                if (row < M_real)
                    C[(size_t)row * N + col] = acc[mi][nj][r] + bv;
            }
        }
    }
}

// ---------------------------------------------------------------------------
// Generic f32 GEMM (out proj): C = A @ W^T + bias
// ---------------------------------------------------------------------------
__global__ __launch_bounds__(256) void gemm_atb_kernel(
    const float* __restrict__ A, const float* __restrict__ W,
    const float* __restrict__ bias, float* __restrict__ C,
    int M, int N, int K)
{
    __shared__ float As[16][64];
    __shared__ float Wt[16][64];

    const int tid = threadIdx.x;
    const int m0 = blockIdx.x * 64;
    const int n0 = blockIdx.y * 64;
    const int tx = tid & 15;
    const int ty = tid >> 4;
    const int lr = tid >> 2;
    const int lk = (tid & 3) << 2;

    const int am = m0 + lr;
    const int wn = n0 + lr;

    float acc[4][4] = {};

    for (int k0 = 0; k0 < K; k0 += 16) {
        float4 av = make_float4(0.f, 0.f, 0.f, 0.f);
        float4 wv = make_float4(0.f, 0.f, 0.f, 0.f);
        if (am < M) av = *reinterpret_cast<const float4*>(&A[(size_t)am * K + k0 + lk]);
        if (wn < N) wv = *reinterpret_cast<const float4*>(&W[(size_t)wn * K + k0 + lk]);
        As[lk + 0][lr] = av.x; As[lk + 1][lr] = av.y;
        As[lk + 2][lr] = av.z; As[lk + 3][lr] = av.w;
        Wt[lk + 0][lr] = wv.x; Wt[lk + 1][lr] = wv.y;
        Wt[lk + 2][lr] = wv.z; Wt[lk + 3][lr] = wv.w;
        __syncthreads();

        #pragma unroll
        for (int k = 0; k < 16; ++k) {
            float a[4], b[4];
            #pragma unroll
            for (int i = 0; i < 4; ++i) a[i] = As[k][ty * 4 + i];
            #pragma unroll
            for (int j = 0; j < 4; ++j) b[j] = Wt[k][tx * 4 + j];
            #pragma unroll
            for (int i = 0; i < 4; ++i)
                #pragma unroll
                for (int j = 0; j < 4; ++j)
                    acc[i][j] += a[i] * b[j];
        }
        __syncthreads();
    }

    #pragma unroll
    for (int i = 0; i < 4; ++i) {
        int m = m0 + ty * 4 + i;
        if (m >= M) continue;
        #pragma unroll
        for (int j = 0; j < 4; ++j) {
            int n = n0 + tx * 4 + j;
            if (n >= N) continue;
            float v = acc[i][j];
            if (bias) v += bias[n];
            C[(size_t)m * N + n] = v;
        }
    }
}

// ---------------------------------------------------------------------------
// Deformable sampling, wave-parallel. One block per query row.
//  Phase A : lanes 0-31 compute the 32 ref-proj dots (f32, fused — kills the
//            ref GEMM dispatch); threads 96-255 vector-load attn logits.
//  Phase A2: tid<8 anchors from refv; all: per-head softmax via shfl_xor.
//  Phase B : 640 samples -> 4 PRE-SCALED u32 element offsets (idx*256, done
//            once per sample, not per lane) + attn-folded corner weights.
//  Phase C : thread (h,c): 80 x { 1 ds_read_b128 idx + 1 b128 wcor +
//            4 gathers + 4 fma } — minimal VALU.
// ---------------------------------------------------------------------------
__global__ __launch_bounds__(256) void deform_sample_kernel(
    const float* __restrict__ values,    // (B, TOTAL, NH, HD)
    const float* __restrict__ x,         // (B*SEQ, 256)
    const float* __restrict__ ref_w,     // (32, 256)
    const float* __restrict__ ref_b,     // (32,)
    const float* __restrict__ proj_off,  // (B*SEQ, 1280)
    const float* __restrict__ proj_attn, // (B*SEQ, 640)
    const float* __restrict__ def_refs,  // (NR, 2)
    float* __restrict__ out)             // (B*SEQ, 256)
{
    const int row = blockIdx.x;
    const int b   = row >> 10;           // SEQ = 1024
    const int tid = threadIdx.x;

    __shared__ float  attn_s[NH * NL * NP];           // 640 f32
    __shared__ float  anchors[NH][2];
    __shared__ float  refv[NH * NR];                  // 32 ref logits
    __shared__ __align__(16) unsigned int sidx[NH * NL * NP][4]; // prescaled
    __shared__ float4 wcor[NH * NL * NP];

    // ---- Phase A ----
    if (tid >= 96) {            // 160 threads: vector-load attn logits
        int i = tid - 96;
        reinterpret_cast<float4*>(attn_s)[i] =
            reinterpret_cast<const float4*>(proj_attn + (size_t)row * 640)[i];
    } else if (tid < 32) {      // 32 lanes: ref-proj dots (f32, k ascending)
        float dot = ref_b[tid];
        const float* xr = x + (size_t)row * 256;
        const float* wr = ref_w + (size_t)tid * 256;
        for (int k = 0; k < 256; k += 4) {
            float4 xv = *reinterpret_cast<const float4*>(xr + k);
            float4 wv = *reinterpret_cast<const float4*>(wr + k);
            dot += xv.x * wv.x; dot += xv.y * wv.y;
            dot += xv.z * wv.z; dot += xv.w * wv.w;
        }
        refv[tid] = dot;
    }
    __syncthreads();

    // ---- Phase A2: anchors (tid<8) + per-head softmax over 80 ----
    if (tid < NH) {
        const int h = tid;
        float rv[NR];
        float rmax = -1e30f;
        #pragma unroll
        for (int r = 0; r < NR; ++r) {
            rv[r] = refv[h * NR + r];
            rmax = fmaxf(rmax, rv[r]);
        }
        float rsum = 0.f;
        #pragma unroll
        for (int r = 0; r < NR; ++r) { rv[r] = __expf(rv[r] - rmax); rsum += rv[r]; }
        float ax = 0.f, ay = 0.f;
        #pragma unroll
        for (int r = 0; r < NR; ++r) {
            float pr = rv[r] / rsum;
            float sx = 1.f / (1.f + __expf(-def_refs[r * 2 + 0]));
            float sy = 1.f / (1.f + __expf(-def_refs[r * 2 + 1]));
            ax += pr * sx; ay += pr * sy;
        }
        anchors[h][0] = ax; anchors[h][1] = ay;
    }
    {
        const int g = tid >> 5;   // head
        const int l = tid & 31;
        float v0 = attn_s[g * 80 + l];
        float v1 = attn_s[g * 80 + 32 + l];
        float v2 = (l < 16) ? attn_s[g * 80 + 64 + l] : -1e30f;
        float m = fmaxf(fmaxf(v0, v1), v2);
        #pragma unroll
        for (int d = 16; d >= 1; d >>= 1) m = fmaxf(m, __shfl_xor(m, d, 64));
        float e0 = __expf(v0 - m), e1 = __expf(v1 - m);
        float e2 = (l < 16) ? __expf(v2 - m) : 0.f;
        float s = e0 + e1 + e2;
        #pragma unroll
        for (int d = 16; d >= 1; d >>= 1) s += __shfl_xor(s, d, 64);
        float inv = 1.f / s;
        __syncthreads();   // all reads of raw logits done before overwrite
        attn_s[g * 80 + l]      = e0 * inv;
        attn_s[g * 80 + 32 + l] = e1 * inv;
        if (l < 16) attn_s[g * 80 + 64 + l] = e2 * inv;
    }
    __syncthreads();

    // ---- Phase B: locations -> prescaled u32 offsets + folded weights ----
    const int lhh[NL] = {100, 50, 25, 13};
    const int lww[NL] = {152, 76, 38, 19};
    const int lst[NL] = {0, 15200, 19000, 19950};

    for (int e = tid; e < NH * NL * NP; e += 256) {
        int h = e / 80;
        int rem = e - h * 80;
        int l = rem / 20;
        const float2 o = *reinterpret_cast<const float2*>(
            proj_off + (size_t)row * 1280 + e * 2);
        float offx = tanhf(o.x);
        float offy = tanhf(o.y);
        int ww = lww[l], hh = lhh[l];
        float locx = fminf(fmaxf(anchors[h][0] + offx * (OFF_SCALE / (float)ww), 0.f), 1.f);
        float locy = fminf(fmaxf(anchors[h][1] + offy * (OFF_SCALE / (float)hh), 0.f), 1.f);
        float xx = locx * (float)ww - 0.5f;
        float yy = locy * (float)hh - 0.5f;
        float x0f = floorf(xx), y0f = floorf(yy);
        int x0 = (int)x0f, y0 = (int)y0f;
        float wx = xx - x0f, wy = yy - y0f;
        float wa = attn_s[e];

        float bx0 = (x0 >= 0)      ? 1.f : 0.f;
        float bx1 = (x0 < ww - 1)  ? 1.f : 0.f;
        float by0 = (y0 >= 0)      ? 1.f : 0.f;
        float by1 = (y0 < hh - 1)  ? 1.f : 0.f;
        int xc0 = max(x0, 0), xc1 = min(x0 + 1, ww - 1);
        int yc0 = max(y0, 0), yc1 = min(y0 + 1, hh - 1);
        // element offsets into (TOTAL,256), prescaled by 256 (one mul/sample)
        sidx[e][0] = (unsigned int)(lst[l] + yc0 * ww + xc0) << 8;
        sidx[e][1] = (unsigned int)(lst[l] + yc0 * ww + xc1) << 8;
        sidx[e][2] = (unsigned int)(lst[l] + yc1 * ww + xc0) << 8;
        sidx[e][3] = (unsigned int)(lst[l] + yc1 * ww + xc1) << 8;

        float4 w;
        w.x = wa * (1.f - wx) * (1.f - wy) * bx0 * by0;
        w.y = wa * wx * (1.f - wy) * bx1 * by0;
        w.z = wa * (1.f - wx) * wy * bx0 * by1;
        w.w = wa * wx * wy * bx1 * by1;
        wcor[e] = w;
    }
    __syncthreads();

    // ---- Phase C: gather + accumulate ----
    const int h = tid >> 5;
    const int c = tid & 31;
    const float* vb = values + (size_t)b * TOTAL * 256 + h * 32 + c;
    float acc = 0.f;
    #pragma unroll 4
    for (int i = 0; i < 80; ++i) {
        int e = h * 80 + i;
        uint4 pi = *reinterpret_cast<const uint4*>(&sidx[e][0]);
        float4 w = wcor[e];
        acc += w.x * vb[pi.x];
        acc += w.y * vb[pi.y];
        acc += w.z * vb[pi.z];
        acc += w.w * vb[pi.w];
    }
    out[(size_t)row * 256 + h * 32 + c] = acc;
}

// ---------------------------------------------------------------------------
extern "C" void kernel_launch(void* const* d_in, const int* in_sizes, int n_in,
                              void* d_out, int out_size, void* d_ws, size_t ws_size,
                              hipStream_t stream)
{
    const float* x        = (const float*)d_in[0];
    const float* enc      = (const float*)d_in[1];
    const float* v_w      = (const float*)d_in[2];
    const float* out_w    = (const float*)d_in[3];
    const float* off_w    = (const float*)d_in[4];
    const float* off_b    = (const float*)d_in[5];
    const float* attn_w   = (const float*)d_in[6];
    const float* attn_b   = (const float*)d_in[7];
    const float* ref_w    = (const float*)d_in[8];
    const float* ref_b    = (const float*)d_in[9];
    const float* def_refs = (const float*)d_in[10];
    float* out = (float*)d_out;

    const int M_Q    = BATCH * SEQ;       // 4096
    const int N_OFF  = NH * NL * NP * 2;  // 1280
    const int N_ATTN = NH * NL * NP;      // 640

    // ---- workspace layout (~119.5 MB, no aliasing) ----
    float* ws = (float*)d_ws;
    float* values    = ws;                                    // 82.7 MB
    float* proj_off  = values    + (size_t)M_ENC * EDIM;      // 21.0 MB
    float* proj_attn = proj_off  + (size_t)M_Q * N_OFF;       // 10.5 MB
    float* attn_out  = proj_attn + (size_t)M_Q * N_ATTN;      //  4.2 MB
    unsigned short* vw_bf16    = (unsigned short*)(attn_out + (size_t)M_Q * EDIM);
    unsigned short* offw_bf16  = vw_bf16   + (size_t)EDIM * KDIM;
    unsigned short* attnw_bf16 = offw_bf16 + (size_t)N_OFF * KDIM;

    dim3 blk(256);

    // 1) all weight casts, one dispatch
    cast3_kernel<<<dim3(272), blk, 0, stream>>>(
        v_w, vw_bf16, (long)EDIM * KDIM,
        off_w, offw_bf16, (long)N_OFF * KDIM,
        attn_w, attnw_bf16, (long)N_ATTN * KDIM);

    // 2) values = enc @ v_w^T (pipelined fused-cast MFMA)
    gemm_mfma_f32a_kernel<<<dim3((M_ENC + 127) / 128, EDIM / 128), blk, 0, stream>>>(
        enc, vw_bf16, nullptr, values, M_ENC, EDIM);

    // 3) projections: off + attn (pipelined MFMA, bias fused)
    gemm_mfma_f32a_kernel<<<dim3(M_Q / 128, N_OFF / 128), blk, 0, stream>>>(
        x, offw_bf16, off_b, proj_off, M_Q, N_OFF);
    gemm_mfma_f32a_kernel<<<dim3(M_Q / 128, N_ATTN / 128), blk, 0, stream>>>(
        x, attnw_bf16, attn_b, proj_attn, M_Q, N_ATTN);

    // 4) deformable sampling (ref-proj fused in)
    deform_sample_kernel<<<dim3(M_Q), blk, 0, stream>>>(
        values, x, ref_w, ref_b, proj_off, proj_attn, def_refs, attn_out);

    // 5) out = attn_out @ out_w^T (f32)
    gemm_atb_kernel<<<dim3(M_Q / 64, EDIM / 64), blk, 0, stream>>>(
        attn_out, out_w, nullptr, out, M_Q, EDIM, EDIM);
}

// Round 10
// 329.270 us; speedup vs baseline: 1.0161x; 1.0011x over previous
//
#include <hip/hip_runtime.h>
#include <hip/hip_bf16.h>
#include <math.h>

#define NH 8
#define HD 32
#define EDIM 256
#define NL 4
#define NP 20
#define NR 4
#define SEQ 1024
#define BATCH 4
#define TOTAL 20197
#define OFF_SCALE 4.0f

#define M_ENC (BATCH * TOTAL)   // 80788
#define KDIM 256
#define LDSW 40                 // padded LDS row stride (bf16): 80B

typedef short bf16x8 __attribute__((ext_vector_type(8)));
typedef float f32x4  __attribute__((ext_vector_type(4)));

__device__ __forceinline__ unsigned short f32_to_bf16_rne(float f) {
    unsigned u = __float_as_uint(f);
    return (unsigned short)((u + 0x7fffu + ((u >> 16) & 1u)) >> 16);
}

// ---------------------------------------------------------------------------
// Triple f32 -> bf16 cast (RNE), grid-stride. Sizes divisible by 8; n2 may
// be 0 (third stream unused).
// ---------------------------------------------------------------------------
__global__ __launch_bounds__(256) void cast3_kernel(
    const float* __restrict__ s0, unsigned short* __restrict__ d0, long n0,
    const float* __restrict__ s1, unsigned short* __restrict__ d1, long n1,
    const float* __restrict__ s2, unsigned short* __restrict__ d2, long n2)
{
    long c0 = n0 >> 3, c1 = n1 >> 3, c2 = n2 >> 3;
    long total = c0 + c1 + c2;
    long gid = (long)blockIdx.x * blockDim.x + threadIdx.x;
    long stride = (long)gridDim.x * blockDim.x;
    for (long i = gid; i < total; i += stride) {
        const float* s; unsigned short* d; long e;
        if (i < c0)            { s = s0; d = d0; e = i * 8; }
        else if (i < c0 + c1)  { s = s1; d = d1; e = (i - c0) * 8; }
        else                   { s = s2; d = d2; e = (i - c0 - c1) * 8; }
        float4 a = *reinterpret_cast<const float4*>(s + e);
        float4 b = *reinterpret_cast<const float4*>(s + e + 4);
        float f[8] = {a.x, a.y, a.z, a.w, b.x, b.y, b.z, b.w};
        unsigned short o[8];
        #pragma unroll
        for (int j = 0; j < 8; ++j) o[j] = f32_to_bf16_rne(f[j]);
        *reinterpret_cast<uint4*>(d + e) = *reinterpret_cast<const uint4*>(o);
    }
}

// ---------------------------------------------------------------------------
// bf16-A MFMA GEMM (round-6 structure + LDSW pad + row guards):
//   C[m][n] = sum_k A_bf16[m][k]*W_bf16[n][k] + bias[n];  f32 out.
// A: (M,256) bf16, W: (N,256) bf16 row-major, N mult of 128.
// 128x128 tile, BK=32, 4 waves, single-buffered reg-staged LDS (20KB).
// ---------------------------------------------------------------------------
__global__ __launch_bounds__(256) void gemm_bf16a_kernel(
    const unsigned short* __restrict__ A,
    const unsigned short* __restrict__ W,
    const float* __restrict__ bias,
    float* __restrict__ C,
    int M_real, int N)
{
    __shared__ __align__(16) unsigned short As[128 * LDSW];
    __shared__ __align__(16) unsigned short Ws[128 * LDSW];

    const int tid  = threadIdx.x;
    const int m0   = blockIdx.x * 128;
    const int n0   = blockIdx.y * 128;
    const int wave = tid >> 6;
    const int lane = tid & 63;
    const int wr   = wave >> 1;
    const int wc   = wave & 1;
    const int lrow = lane & 15;
    const int kg   = lane >> 4;

    f32x4 acc[4][4] = {};

    for (int k0 = 0; k0 < KDIM; k0 += 32) {
        #pragma unroll
        for (int it = 0; it < 2; ++it) {
            int s   = tid + it * 256;   // 16B slot in [0,512)
            int row = s >> 2;
            int ks  = s & 3;
            int gm  = m0 + row;
            uint4 va = make_uint4(0u, 0u, 0u, 0u);
            if (gm < M_real)
                va = *reinterpret_cast<const uint4*>(
                    A + (size_t)gm * KDIM + k0 + ks * 8);
            uint4 vw = *reinterpret_cast<const uint4*>(
                W + (size_t)(n0 + row) * KDIM + k0 + ks * 8);
            *reinterpret_cast<uint4*>(&As[row * LDSW + ks * 8]) = va;
            *reinterpret_cast<uint4*>(&Ws[row * LDSW + ks * 8]) = vw;
        }
        __syncthreads();

        bf16x8 af[4], bfr[4];
        #pragma unroll
        for (int mi = 0; mi < 4; ++mi)
            af[mi] = *reinterpret_cast<const bf16x8*>(
                &As[(wr * 64 + mi * 16 + lrow) * LDSW + kg * 8]);
        #pragma unroll
        for (int nj = 0; nj < 4; ++nj)
            bfr[nj] = *reinterpret_cast<const bf16x8*>(
                &Ws[(wc * 64 + nj * 16 + lrow) * LDSW + kg * 8]);
        #pragma unroll
        for (int mi = 0; mi < 4; ++mi)
            #pragma unroll
            for (int nj = 0; nj < 4; ++nj)
                acc[mi][nj] = __builtin_amdgcn_mfma_f32_16x16x32_bf16(
                    af[mi], bfr[nj], acc[mi][nj], 0, 0, 0);
        __syncthreads();
    }

    #pragma unroll
    for (int mi = 0; mi < 4; ++mi) {
        #pragma unroll
        for (int nj = 0; nj < 4; ++nj) {
            int row_base = m0 + wr * 64 + mi * 16 + kg * 4;
            int col      = n0 + wc * 64 + nj * 16 + lrow;
            float bv = bias ? bias[col] : 0.f;
            #pragma unroll
            for (int r = 0; r < 4; ++r) {
                int row = row_base + r;
                if (row < M_real)
                    C[(size_t)row * N + col] = acc[mi][nj][r] + bv;
            }
        }
    }
}

// ---------------------------------------------------------------------------
// Fused-cast f32-A MFMA GEMM (round-8 single-buffer version) — used for the
// small-M projection GEMMs only. C = A_f32 @ W_bf16^T + bias.
// ---------------------------------------------------------------------------
__global__ __launch_bounds__(256) void gemm_mfma_f32a_kernel(
    const float* __restrict__ A,
    const unsigned short* __restrict__ W,
    const float* __restrict__ bias,
    float* __restrict__ C,
    int M_real, int N)
{
    __shared__ __align__(16) unsigned short As[128 * LDSW];
    __shared__ __align__(16) unsigned short Ws[128 * LDSW];

    const int tid  = threadIdx.x;
    const int m0   = blockIdx.x * 128;
    const int n0   = blockIdx.y * 128;
    const int wave = tid >> 6;
    const int lane = tid & 63;
    const int wr   = wave >> 1;
    const int wc   = wave & 1;
    const int lrow = lane & 15;
    const int kg   = lane >> 4;

    f32x4 acc[4][4] = {};

    for (int k0 = 0; k0 < KDIM; k0 += 32) {
        #pragma unroll
        for (int p = 0; p < 4; ++p) {
            int s   = tid + p * 256;
            int row = s >> 3;
            int sl  = s & 7;
            int gm  = m0 + row;
            float4 v = make_float4(0.f, 0.f, 0.f, 0.f);
            if (gm < M_real)
                v = *reinterpret_cast<const float4*>(&A[(size_t)gm * KDIM + k0 + sl * 4]);
            unsigned short o[4] = {
                f32_to_bf16_rne(v.x), f32_to_bf16_rne(v.y),
                f32_to_bf16_rne(v.z), f32_to_bf16_rne(v.w)};
            *reinterpret_cast<uint2*>(&As[row * LDSW + sl * 4]) =
                *reinterpret_cast<const uint2*>(o);
        }
        #pragma unroll
        for (int it = 0; it < 2; ++it) {
            int s   = tid + it * 256;
            int row = s >> 2;
            int ks  = s & 3;
            uint4 vw = *reinterpret_cast<const uint4*>(
                W + (size_t)(n0 + row) * KDIM + k0 + ks * 8);
            *reinterpret_cast<uint4*>(&Ws[row * LDSW + ks * 8]) = vw;
        }
        __syncthreads();

        bf16x8 af[4], bfr[4];
        #pragma unroll
        for (int mi = 0; mi < 4; ++mi)
            af[mi] = *reinterpret_cast<const bf16x8*>(
                &As[(wr * 64 + mi * 16 + lrow) * LDSW + kg * 8]);
        #pragma unroll
        for (int nj = 0; nj < 4; ++nj)
            bfr[nj] = *reinterpret_cast<const bf16x8*>(
                &Ws[(wc * 64 + nj * 16 + lrow) * LDSW + kg * 8]);
        #pragma unroll
        for (int mi = 0; mi < 4; ++mi)
            #pragma unroll
            for (int nj = 0; nj < 4; ++nj)
                acc[mi][nj] = __builtin_amdgcn_mfma_f32_16x16x32_bf16(
                    af[mi], bfr[nj], acc[mi][nj], 0, 0, 0);
        __syncthreads();
    }

    #pragma unroll
    for (int mi = 0; mi < 4; ++mi) {
        #pragma unroll
        for (int nj = 0; nj < 4; ++nj) {
            int row_base = m0 + wr * 64 + mi * 16 + kg * 4;
            int col      = n0 + wc * 64 + nj * 16 + lrow;
            float bv = bias ? bias[col] : 0.f;
            #pragma unroll
            for (int r = 0; r < 4; ++r) {
                int row = row_base + r;
                if (row < M_real)
                    C[(size_t)row * N + col] = acc[mi][nj][r] + bv;
            }
        }
    }
}

// ---------------------------------------------------------------------------
// Deformable sampling, wave-parallel (r9 version; output now bf16).
// ---------------------------------------------------------------------------
__global__ __launch_bounds__(256) void deform_sample_kernel(
    const float* __restrict__ values,    // (B, TOTAL, NH, HD) f32
    const float* __restrict__ x,         // (B*SEQ, 256)
    const float* __restrict__ ref_w,     // (32, 256)
    const float* __restrict__ ref_b,     // (32,)
    const float* __restrict__ proj_off,  // (B*SEQ, 1280)
    const float* __restrict__ proj_attn, // (B*SEQ, 640)
    const float* __restrict__ def_refs,  // (NR, 2)
    unsigned short* __restrict__ out)    // (B*SEQ, 256) bf16
{
    const int row = blockIdx.x;
    const int b   = row >> 10;           // SEQ = 1024
    const int tid = threadIdx.x;

    __shared__ float  attn_s[NH * NL * NP];           // 640 f32
    __shared__ float  anchors[NH][2];
    __shared__ float  refv[NH * NR];                  // 32 ref logits
    __shared__ __align__(16) unsigned int sidx[NH * NL * NP][4]; // prescaled
    __shared__ float4 wcor[NH * NL * NP];

    // ---- Phase A ----
    if (tid >= 96) {            // 160 threads: vector-load attn logits
        int i = tid - 96;
        reinterpret_cast<float4*>(attn_s)[i] =
            reinterpret_cast<const float4*>(proj_attn + (size_t)row * 640)[i];
    } else if (tid < 32) {      // 32 lanes: ref-proj dots (f32, k ascending)
        float dot = ref_b[tid];
        const float* xr = x + (size_t)row * 256;
        const float* wr = ref_w + (size_t)tid * 256;
        for (int k = 0; k < 256; k += 4) {
            float4 xv = *reinterpret_cast<const float4*>(xr + k);
            float4 wv = *reinterpret_cast<const float4*>(wr + k);
            dot += xv.x * wv.x; dot += xv.y * wv.y;
            dot += xv.z * wv.z; dot += xv.w * wv.w;
        }
        refv[tid] = dot;
    }
    __syncthreads();

    // ---- Phase A2: anchors (tid<8) + per-head softmax over 80 ----
    if (tid < NH) {
        const int h = tid;
        float rv[NR];
        float rmax = -1e30f;
        #pragma unroll
        for (int r = 0; r < NR; ++r) {
            rv[r] = refv[h * NR + r];
            rmax = fmaxf(rmax, rv[r]);
        }
        float rsum = 0.f;
        #pragma unroll
        for (int r = 0; r < NR; ++r) { rv[r] = __expf(rv[r] - rmax); rsum += rv[r]; }
        float ax = 0.f, ay = 0.f;
        #pragma unroll
        for (int r = 0; r < NR; ++r) {
            float pr = rv[r] / rsum;
            float sx = 1.f / (1.f + __expf(-def_refs[r * 2 + 0]));
            float sy = 1.f / (1.f + __expf(-def_refs[r * 2 + 1]));
            ax += pr * sx; ay += pr * sy;
        }
        anchors[h][0] = ax; anchors[h][1] = ay;
    }
    {
        const int g = tid >> 5;   // head
        const int l = tid & 31;
        float v0 = attn_s[g * 80 + l];
        float v1 = attn_s[g * 80 + 32 + l];
        float v2 = (l < 16) ? attn_s[g * 80 + 64 + l] : -1e30f;
        float m = fmaxf(fmaxf(v0, v1), v2);
        #pragma unroll
        for (int d = 16; d >= 1; d >>= 1) m = fmaxf(m, __shfl_xor(m, d, 64));
        float e0 = __expf(v0 - m), e1 = __expf(v1 - m);
        float e2 = (l < 16) ? __expf(v2 - m) : 0.f;
        float s = e0 + e1 + e2;
        #pragma unroll
        for (int d = 16; d >= 1; d >>= 1) s += __shfl_xor(s, d, 64);
        float inv = 1.f / s;
        __syncthreads();   // all reads of raw logits done before overwrite
        attn_s[g * 80 + l]      = e0 * inv;
        attn_s[g * 80 + 32 + l] = e1 * inv;
        if (l < 16) attn_s[g * 80 + 64 + l] = e2 * inv;
    }
    __syncthreads();

    // ---- Phase B: locations -> prescaled u32 offsets + folded weights ----
    const int lhh[NL] = {100, 50, 25, 13};
    const int lww[NL] = {152, 76, 38, 19};
    const int lst[NL] = {0, 15200, 19000, 19950};

    for (int e = tid; e < NH * NL * NP; e += 256) {
        int h = e / 80;
        int rem = e - h * 80;
        int l = rem / 20;
        const float2 o = *reinterpret_cast<const float2*>(
            proj_off + (size_t)row * 1280 + e * 2);
        float offx = tanhf(o.x);
        float offy = tanhf(o.y);
        int ww = lww[l], hh = lhh[l];
        float locx = fminf(fmaxf(anchors[h][0] + offx * (OFF_SCALE / (float)ww), 0.f), 1.f);
        float locy = fminf(fmaxf(anchors[h][1] + offy * (OFF_SCALE / (float)hh), 0.f), 1.f);
        float xx = locx * (float)ww - 0.5f;
        float yy = locy * (float)hh - 0.5f;
        float x0f = floorf(xx), y0f = floorf(yy);
        int x0 = (int)x0f, y0 = (int)y0f;
        float wx = xx - x0f, wy = yy - y0f;
        float wa = attn_s[e];

        float bx0 = (x0 >= 0)      ? 1.f : 0.f;
        float bx1 = (x0 < ww - 1)  ? 1.f : 0.f;
        float by0 = (y0 >= 0)      ? 1.f : 0.f;
        float by1 = (y0 < hh - 1)  ? 1.f : 0.f;
        int xc0 = max(x0, 0), xc1 = min(x0 + 1, ww - 1);
        int yc0 = max(y0, 0), yc1 = min(y0 + 1, hh - 1);
        sidx[e][0] = (unsigned int)(lst[l] + yc0 * ww + xc0) << 8;
        sidx[e][1] = (unsigned int)(lst[l] + yc0 * ww + xc1) << 8;
        sidx[e][2] = (unsigned int)(lst[l] + yc1 * ww + xc0) << 8;
        sidx[e][3] = (unsigned int)(lst[l] + yc1 * ww + xc1) << 8;

        float4 w;
        w.x = wa * (1.f - wx) * (1.f - wy) * bx0 * by0;
        w.y = wa * wx * (1.f - wy) * bx1 * by0;
        w.z = wa * (1.f - wx) * wy * bx0 * by1;
        w.w = wa * wx * wy * bx1 * by1;
        wcor[e] = w;
    }
    __syncthreads();

    // ---- Phase C: gather + accumulate, write bf16 ----
    const int h = tid >> 5;
    const int c = tid & 31;
    const float* vb = values + (size_t)b * TOTAL * 256 + h * 32 + c;
    float acc = 0.f;
    #pragma unroll 4
    for (int i = 0; i < 80; ++i) {
        int e = h * 80 + i;
        uint4 pi = *reinterpret_cast<const uint4*>(&sidx[e][0]);
        float4 w = wcor[e];
        acc += w.x * vb[pi.x];
        acc += w.y * vb[pi.y];
        acc += w.z * vb[pi.z];
        acc += w.w * vb[pi.w];
    }
    out[(size_t)row * 256 + h * 32 + c] = f32_to_bf16_rne(acc);
}

// ---------------------------------------------------------------------------
extern "C" void kernel_launch(void* const* d_in, const int* in_sizes, int n_in,
                              void* d_out, int out_size, void* d_ws, size_t ws_size,
                              hipStream_t stream)
{
    const float* x        = (const float*)d_in[0];
    const float* enc      = (const float*)d_in[1];
    const float* v_w      = (const float*)d_in[2];
    const float* out_w    = (const float*)d_in[3];
    const float* off_w    = (const float*)d_in[4];
    const float* off_b    = (const float*)d_in[5];
    const float* attn_w   = (const float*)d_in[6];
    const float* attn_b   = (const float*)d_in[7];
    const float* ref_w    = (const float*)d_in[8];
    const float* ref_b    = (const float*)d_in[9];
    const float* def_refs = (const float*)d_in[10];
    float* out = (float*)d_out;

    const int M_Q    = BATCH * SEQ;       // 4096
    const int N_OFF  = NH * NL * NP * 2;  // 1280
    const int N_ATTN = NH * NL * NP;      // 640

    // ---- workspace layout (peak 124.2 MB; r6-proven size) ----
    // [values f32 82.73MB][enc_region 41.36MB][vw_bf16 0.13MB]
    // enc_region: first holds enc_bf16 (dead after values GEMM), then:
    //   proj_off(20.97) proj_attn(10.49) attn_out_bf16(2.10)
    //   offw(0.655) attnw(0.328) outw(0.131) = 34.67MB — cast AFTER values GEMM
    float* ws = (float*)d_ws;
    float* values = ws;
    char*  region = (char*)(values + (size_t)M_ENC * EDIM);
    unsigned short* enc_bf16 = (unsigned short*)region;
    float* proj_off  = (float*)region;
    float* proj_attn = proj_off  + (size_t)M_Q * N_OFF;
    unsigned short* attn_out_bf16 = (unsigned short*)(proj_attn + (size_t)M_Q * N_ATTN);
    unsigned short* offw_bf16  = attn_out_bf16 + (size_t)M_Q * EDIM;
    unsigned short* attnw_bf16 = offw_bf16  + (size_t)N_OFF * KDIM;
    unsigned short* outw_bf16  = attnw_bf16 + (size_t)N_ATTN * KDIM;
    unsigned short* vw_bf16 = (unsigned short*)(region + (size_t)M_ENC * KDIM * 2);

    dim3 blk(256);

    // 1) cast enc + v_w -> bf16 (streaming, pure BW)
    cast3_kernel<<<dim3(2048), blk, 0, stream>>>(
        enc, enc_bf16, (long)M_ENC * KDIM,
        v_w, vw_bf16, (long)EDIM * KDIM,
        v_w, vw_bf16, 0L);

    // 2) values = enc @ v_w^T  (bf16-A MFMA, f32 out)
    gemm_bf16a_kernel<<<dim3((M_ENC + 127) / 128, EDIM / 128), blk, 0, stream>>>(
        enc_bf16, vw_bf16, nullptr, values, M_ENC, EDIM);

    // 3) cast remaining weights into the (now dead) enc region
    cast3_kernel<<<dim3(288), blk, 0, stream>>>(
        off_w, offw_bf16, (long)N_OFF * KDIM,
        attn_w, attnw_bf16, (long)N_ATTN * KDIM,
        out_w, outw_bf16, (long)EDIM * KDIM);

    // 4) projections: off + attn via fused f32-A MFMA (bias fused)
    gemm_mfma_f32a_kernel<<<dim3(M_Q / 128, N_OFF / 128), blk, 0, stream>>>(
        x, offw_bf16, off_b, proj_off, M_Q, N_OFF);
    gemm_mfma_f32a_kernel<<<dim3(M_Q / 128, N_ATTN / 128), blk, 0, stream>>>(
        x, attnw_bf16, attn_b, proj_attn, M_Q, N_ATTN);

    // 5) deformable sampling (ref-proj fused; writes bf16)
    deform_sample_kernel<<<dim3(M_Q), blk, 0, stream>>>(
        values, x, ref_w, ref_b, proj_off, proj_attn, def_refs, attn_out_bf16);

    // 6) out = attn_out @ out_w^T  (bf16-A MFMA, f32 out)
    gemm_bf16a_kernel<<<dim3(M_Q / 128, EDIM / 128), blk, 0, stream>>>(
        attn_out_bf16, outw_bf16, nullptr, out, M_Q, EDIM);
}

// Round 11
// 292.851 us; speedup vs baseline: 1.1425x; 1.1244x over previous
//
#include <hip/hip_runtime.h>
#include <hip/hip_bf16.h>
#include <math.h>

#define NH 8
#define HD 32
#define EDIM 256
#define NL 4
#define NP 20
#define NR 4
#define SEQ 1024
#define BATCH 4
#define TOTAL 20197
#define OFF_SCALE 4.0f

#define M_ENC (BATCH * TOTAL)   // 80788
#define KDIM 256
#define LDSW 40                 // padded LDS row stride (bf16): 80B
#define N_Q 1920                // merged projection width: off(1280) + attn(640)

typedef short bf16x8 __attribute__((ext_vector_type(8)));
typedef float f32x4  __attribute__((ext_vector_type(4)));

__device__ __forceinline__ unsigned short f32_to_bf16_rne(float f) {
    unsigned u = __float_as_uint(f);
    return (unsigned short)((u + 0x7fffu + ((u >> 16) & 1u)) >> 16);
}
__device__ __forceinline__ float bf16_to_f32(unsigned short u) {
    return __uint_as_float((unsigned)u << 16);
}

// ---------------------------------------------------------------------------
// Quad f32 -> bf16 weight cast (RNE), one dispatch. Sizes divisible by 8.
// ---------------------------------------------------------------------------
__global__ __launch_bounds__(256) void cast4_kernel(
    const float* __restrict__ s0, unsigned short* __restrict__ d0, long n0,
    const float* __restrict__ s1, unsigned short* __restrict__ d1, long n1,
    const float* __restrict__ s2, unsigned short* __restrict__ d2, long n2,
    const float* __restrict__ s3, unsigned short* __restrict__ d3, long n3)
{
    long c0 = n0 >> 3, c1 = n1 >> 3, c2 = n2 >> 3, c3 = n3 >> 3;
    long total = c0 + c1 + c2 + c3;
    long gid = (long)blockIdx.x * blockDim.x + threadIdx.x;
    long stride = (long)gridDim.x * blockDim.x;
    for (long i = gid; i < total; i += stride) {
        const float* s; unsigned short* d; long e;
        if (i < c0)                 { s = s0; d = d0; e = i * 8; }
        else if (i < c0 + c1)       { s = s1; d = d1; e = (i - c0) * 8; }
        else if (i < c0 + c1 + c2)  { s = s2; d = d2; e = (i - c0 - c1) * 8; }
        else                        { s = s3; d = d3; e = (i - c0 - c1 - c2) * 8; }
        float4 a = *reinterpret_cast<const float4*>(s + e);
        float4 b = *reinterpret_cast<const float4*>(s + e + 4);
        float f[8] = {a.x, a.y, a.z, a.w, b.x, b.y, b.z, b.w};
        unsigned short o[8];
        #pragma unroll
        for (int j = 0; j < 8; ++j) o[j] = f32_to_bf16_rne(f[j]);
        *reinterpret_cast<uint4*>(d + e) = *reinterpret_cast<const uint4*>(o);
    }
}

// ---------------------------------------------------------------------------
// Fused-cast f32-A MFMA GEMM, f32 out, split bias:
//   C[m][n] = sum_k bf16(A_f32[m][k]) * W_bf16[n][k] + bias(n)
// bias(n) = n < bsplit ? b0[n] : b1[n - bsplit]   (b0==null -> no bias)
// ---------------------------------------------------------------------------
__global__ __launch_bounds__(256) void gemm_f32a_f32out_kernel(
    const float* __restrict__ A,
    const unsigned short* __restrict__ W,
    const float* __restrict__ b0, const float* __restrict__ b1, int bsplit,
    float* __restrict__ C,
    int M_real, int N)
{
    __shared__ __align__(16) unsigned short As[128 * LDSW];
    __shared__ __align__(16) unsigned short Ws[128 * LDSW];

    const int tid  = threadIdx.x;
    const int m0   = blockIdx.x * 128;
    const int n0   = blockIdx.y * 128;
    const int wave = tid >> 6;
    const int lane = tid & 63;
    const int wr   = wave >> 1;
    const int wc   = wave & 1;
    const int lrow = lane & 15;
    const int kg   = lane >> 4;

    f32x4 acc[4][4] = {};

    for (int k0 = 0; k0 < KDIM; k0 += 32) {
        #pragma unroll
        for (int p = 0; p < 4; ++p) {
            int s   = tid + p * 256;
            int row = s >> 3;
            int sl  = s & 7;
            int gm  = m0 + row;
            float4 v = make_float4(0.f, 0.f, 0.f, 0.f);
            if (gm < M_real)
                v = *reinterpret_cast<const float4*>(&A[(size_t)gm * KDIM + k0 + sl * 4]);
            unsigned short o[4] = {
                f32_to_bf16_rne(v.x), f32_to_bf16_rne(v.y),
                f32_to_bf16_rne(v.z), f32_to_bf16_rne(v.w)};
            *reinterpret_cast<uint2*>(&As[row * LDSW + sl * 4]) =
                *reinterpret_cast<const uint2*>(o);
        }
        #pragma unroll
        for (int it = 0; it < 2; ++it) {
            int s   = tid + it * 256;
            int row = s >> 2;
            int ks  = s & 3;
            uint4 vw = *reinterpret_cast<const uint4*>(
                W + (size_t)(n0 + row) * KDIM + k0 + ks * 8);
            *reinterpret_cast<uint4*>(&Ws[row * LDSW + ks * 8]) = vw;
        }
        __syncthreads();

        bf16x8 af[4], bfr[4];
        #pragma unroll
        for (int mi = 0; mi < 4; ++mi)
            af[mi] = *reinterpret_cast<const bf16x8*>(
                &As[(wr * 64 + mi * 16 + lrow) * LDSW + kg * 8]);
        #pragma unroll
        for (int nj = 0; nj < 4; ++nj)
            bfr[nj] = *reinterpret_cast<const bf16x8*>(
                &Ws[(wc * 64 + nj * 16 + lrow) * LDSW + kg * 8]);
        #pragma unroll
        for (int mi = 0; mi < 4; ++mi)
            #pragma unroll
            for (int nj = 0; nj < 4; ++nj)
                acc[mi][nj] = __builtin_amdgcn_mfma_f32_16x16x32_bf16(
                    af[mi], bfr[nj], acc[mi][nj], 0, 0, 0);
        __syncthreads();
    }

    #pragma unroll
    for (int mi = 0; mi < 4; ++mi) {
        #pragma unroll
        for (int nj = 0; nj < 4; ++nj) {
            int row_base = m0 + wr * 64 + mi * 16 + kg * 4;
            int col      = n0 + wc * 64 + nj * 16 + lrow;
            float bv = 0.f;
            if (b0) bv = (col < bsplit) ? b0[col] : b1[col - bsplit];
            #pragma unroll
            for (int r = 0; r < 4; ++r) {
                int row = row_base + r;
                if (row < M_real)
                    C[(size_t)row * N + col] = acc[mi][nj][r] + bv;
            }
        }
    }
}

// ---------------------------------------------------------------------------
// Fused-cast f32-A MFMA GEMM, bf16 out, no bias (values GEMM).
// ---------------------------------------------------------------------------
__global__ __launch_bounds__(256) void gemm_f32a_bf16out_kernel(
    const float* __restrict__ A,
    const unsigned short* __restrict__ W,
    unsigned short* __restrict__ C,
    int M_real, int N)
{
    __shared__ __align__(16) unsigned short As[128 * LDSW];
    __shared__ __align__(16) unsigned short Ws[128 * LDSW];

    const int tid  = threadIdx.x;
    const int m0   = blockIdx.x * 128;
    const int n0   = blockIdx.y * 128;
    const int wave = tid >> 6;
    const int lane = tid & 63;
    const int wr   = wave >> 1;
    const int wc   = wave & 1;
    const int lrow = lane & 15;
    const int kg   = lane >> 4;

    f32x4 acc[4][4] = {};

    for (int k0 = 0; k0 < KDIM; k0 += 32) {
        #pragma unroll
        for (int p = 0; p < 4; ++p) {
            int s   = tid + p * 256;
            int row = s >> 3;
            int sl  = s & 7;
            int gm  = m0 + row;
            float4 v = make_float4(0.f, 0.f, 0.f, 0.f);
            if (gm < M_real)
                v = *reinterpret_cast<const float4*>(&A[(size_t)gm * KDIM + k0 + sl * 4]);
            unsigned short o[4] = {
                f32_to_bf16_rne(v.x), f32_to_bf16_rne(v.y),
                f32_to_bf16_rne(v.z), f32_to_bf16_rne(v.w)};
            *reinterpret_cast<uint2*>(&As[row * LDSW + sl * 4]) =
                *reinterpret_cast<const uint2*>(o);
        }
        #pragma unroll
        for (int it = 0; it < 2; ++it) {
            int s   = tid + it * 256;
            int row = s >> 2;
            int ks  = s & 3;
            uint4 vw = *reinterpret_cast<const uint4*>(
                W + (size_t)(n0 + row) * KDIM + k0 + ks * 8);
            *reinterpret_cast<uint4*>(&Ws[row * LDSW + ks * 8]) = vw;
        }
        __syncthreads();

        bf16x8 af[4], bfr[4];
        #pragma unroll
        for (int mi = 0; mi < 4; ++mi)
            af[mi] = *reinterpret_cast<const bf16x8*>(
                &As[(wr * 64 + mi * 16 + lrow) * LDSW + kg * 8]);
        #pragma unroll
        for (int nj = 0; nj < 4; ++nj)
            bfr[nj] = *reinterpret_cast<const bf16x8*>(
                &Ws[(wc * 64 + nj * 16 + lrow) * LDSW + kg * 8]);
        #pragma unroll
        for (int mi = 0; mi < 4; ++mi)
            #pragma unroll
            for (int nj = 0; nj < 4; ++nj)
                acc[mi][nj] = __builtin_amdgcn_mfma_f32_16x16x32_bf16(
                    af[mi], bfr[nj], acc[mi][nj], 0, 0, 0);
        __syncthreads();
    }

    #pragma unroll
    for (int mi = 0; mi < 4; ++mi) {
        #pragma unroll
        for (int nj = 0; nj < 4; ++nj) {
            int row_base = m0 + wr * 64 + mi * 16 + kg * 4;
            int col      = n0 + wc * 64 + nj * 16 + lrow;
            #pragma unroll
            for (int r = 0; r < 4; ++r) {
                int row = row_base + r;
                if (row < M_real)
                    C[(size_t)row * N + col] = f32_to_bf16_rne(acc[mi][nj][r]);
            }
        }
    }
}

// ---------------------------------------------------------------------------
// bf16-A MFMA GEMM, f32 out (out projection). M mult of 128 assumed guarded.
// ---------------------------------------------------------------------------
__global__ __launch_bounds__(256) void gemm_bf16a_kernel(
    const unsigned short* __restrict__ A,
    const unsigned short* __restrict__ W,
    float* __restrict__ C,
    int M_real, int N)
{
    __shared__ __align__(16) unsigned short As[128 * LDSW];
    __shared__ __align__(16) unsigned short Ws[128 * LDSW];

    const int tid  = threadIdx.x;
    const int m0   = blockIdx.x * 128;
    const int n0   = blockIdx.y * 128;
    const int wave = tid >> 6;
    const int lane = tid & 63;
    const int wr   = wave >> 1;
    const int wc   = wave & 1;
    const int lrow = lane & 15;
    const int kg   = lane >> 4;

    f32x4 acc[4][4] = {};

    for (int k0 = 0; k0 < KDIM; k0 += 32) {
        #pragma unroll
        for (int it = 0; it < 2; ++it) {
            int s   = tid + it * 256;
            int row = s >> 2;
            int ks  = s & 3;
            int gm  = m0 + row;
            uint4 va = make_uint4(0u, 0u, 0u, 0u);
            if (gm < M_real)
                va = *reinterpret_cast<const uint4*>(
                    A + (size_t)gm * KDIM + k0 + ks * 8);
            uint4 vw = *reinterpret_cast<const uint4*>(
                W + (size_t)(n0 + row) * KDIM + k0 + ks * 8);
            *reinterpret_cast<uint4*>(&As[row * LDSW + ks * 8]) = va;
            *reinterpret_cast<uint4*>(&Ws[row * LDSW + ks * 8]) = vw;
        }
        __syncthreads();

        bf16x8 af[4], bfr[4];
        #pragma unroll
        for (int mi = 0; mi < 4; ++mi)
            af[mi] = *reinterpret_cast<const bf16x8*>(
                &As[(wr * 64 + mi * 16 + lrow) * LDSW + kg * 8]);
        #pragma unroll
        for (int nj = 0; nj < 4; ++nj)
            bfr[nj] = *reinterpret_cast<const bf16x8*>(
                &Ws[(wc * 64 + nj * 16 + lrow) * LDSW + kg * 8]);
        #pragma unroll
        for (int mi = 0; mi < 4; ++mi)
            #pragma unroll
            for (int nj = 0; nj < 4; ++nj)
                acc[mi][nj] = __builtin_amdgcn_mfma_f32_16x16x32_bf16(
                    af[mi], bfr[nj], acc[mi][nj], 0, 0, 0);
        __syncthreads();
    }

    #pragma unroll
    for (int mi = 0; mi < 4; ++mi) {
        #pragma unroll
        for (int nj = 0; nj < 4; ++nj) {
            int row_base = m0 + wr * 64 + mi * 16 + kg * 4;
            int col      = n0 + wc * 64 + nj * 16 + lrow;
            #pragma unroll
            for (int r = 0; r < 4; ++r) {
                int row = row_base + r;
                if (row < M_real)
                    C[(size_t)row * N + col] = acc[mi][nj][r];
            }
        }
    }
}

// ---------------------------------------------------------------------------
// Deformable sampling. One block per query row, 256 threads, 18.1 KB LDS.
//  Phase A : threads 0-63: ref-proj dots, 2 threads/output x 128k unrolled
//            + shfl_xor(1) reduce (parallel, no serial chain);
//            threads 96-255: vector-load attn logits (merged proj row).
//  Phase A2: tid<8 anchors; all: per-head softmax via shfl_xor.
//  Phase B : 640 samples -> u16-packed corner indices + attn-folded weights.
//  Phase C : thread (h,c): 80 x 4 branch-free gathers from bf16 values.
// ---------------------------------------------------------------------------
__global__ __launch_bounds__(256) void deform_sample_kernel(
    const unsigned short* __restrict__ values, // (B, TOTAL, 256) bf16
    const float* __restrict__ x,          // (B*SEQ, 256)
    const float* __restrict__ ref_w,      // (32, 256)
    const float* __restrict__ ref_b,      // (32,)
    const float* __restrict__ proj_q,     // (B*SEQ, 1920): off[0:1280] attn[1280:1920]
    const float* __restrict__ def_refs,   // (NR, 2)
    unsigned short* __restrict__ out)     // (B*SEQ, 256) bf16
{
    const int row = blockIdx.x;
    const int b   = row >> 10;           // SEQ = 1024
    const int tid = threadIdx.x;

    __shared__ float  attn_s[NH * NL * NP];          // 640 f32
    __shared__ float  anchors[NH][2];
    __shared__ float  refv[NH * NR];                 // 32
    __shared__ unsigned int sidx[NH * NL * NP][2];   // 4 x u16 packed
    __shared__ float4 wcor[NH * NL * NP];

    const float* prow = proj_q + (size_t)row * N_Q;

    // ---- Phase A ----
    if (tid >= 96) {            // 160 threads: attn logits (cols 1280..1919)
        int i = tid - 96;
        reinterpret_cast<float4*>(attn_s)[i] =
            reinterpret_cast<const float4*>(prow + 1280)[i];
    } else if (tid < 64) {      // wave 0: ref dots, 2 threads per output
        const int r    = tid >> 1;
        const int half = tid & 1;
        const float* xr = x + (size_t)row * 256 + half * 128;
        const float* wr = ref_w + (size_t)r * 256 + half * 128;
        float dot = 0.f;
        #pragma unroll
        for (int k = 0; k < 128; k += 4) {
            float4 xv = *reinterpret_cast<const float4*>(xr + k);
            float4 wv = *reinterpret_cast<const float4*>(wr + k);
            dot += xv.x * wv.x; dot += xv.y * wv.y;
            dot += xv.z * wv.z; dot += xv.w * wv.w;
        }
        dot += __shfl_xor(dot, 1, 64);
        if (half == 0) refv[r] = dot + ref_b[r];
    }
    __syncthreads();

    // ---- Phase A2: anchors (tid<8) + per-head softmax over 80 ----
    if (tid < NH) {
        const int h = tid;
        float rv[NR];
        float rmax = -1e30f;
        #pragma unroll
        for (int r = 0; r < NR; ++r) {
            rv[r] = refv[h * NR + r];
            rmax = fmaxf(rmax, rv[r]);
        }
        float rsum = 0.f;
        #pragma unroll
        for (int r = 0; r < NR; ++r) { rv[r] = __expf(rv[r] - rmax); rsum += rv[r]; }
        float ax = 0.f, ay = 0.f;
        #pragma unroll
        for (int r = 0; r < NR; ++r) {
            float pr = rv[r] / rsum;
            float sx = 1.f / (1.f + __expf(-def_refs[r * 2 + 0]));
            float sy = 1.f / (1.f + __expf(-def_refs[r * 2 + 1]));
            ax += pr * sx; ay += pr * sy;
        }
        anchors[h][0] = ax; anchors[h][1] = ay;
    }
    {
        const int g = tid >> 5;   // head
        const int l = tid & 31;
        float v0 = attn_s[g * 80 + l];
        float v1 = attn_s[g * 80 + 32 + l];
        float v2 = (l < 16) ? attn_s[g * 80 + 64 + l] : -1e30f;
        float m = fmaxf(fmaxf(v0, v1), v2);
        #pragma unroll
        for (int d = 16; d >= 1; d >>= 1) m = fmaxf(m, __shfl_xor(m, d, 64));
        float e0 = __expf(v0 - m), e1 = __expf(v1 - m);
        float e2 = (l < 16) ? __expf(v2 - m) : 0.f;
        float s = e0 + e1 + e2;
        #pragma unroll
        for (int d = 16; d >= 1; d >>= 1) s += __shfl_xor(s, d, 64);
        float inv = 1.f / s;
        __syncthreads();   // all reads of raw logits done before overwrite
        attn_s[g * 80 + l]      = e0 * inv;
        attn_s[g * 80 + 32 + l] = e1 * inv;
        if (l < 16) attn_s[g * 80 + 64 + l] = e2 * inv;
    }
    __syncthreads();

    // ---- Phase B: locations -> packed u16 indices + folded weights ----
    const int lhh[NL] = {100, 50, 25, 13};
    const int lww[NL] = {152, 76, 38, 19};
    const int lst[NL] = {0, 15200, 19000, 19950};

    for (int e = tid; e < NH * NL * NP; e += 256) {
        int h = e / 80;
        int rem = e - h * 80;
        int l = rem / 20;
        const float2 o = *reinterpret_cast<const float2*>(prow + e * 2);
        float offx = tanhf(o.x);
        float offy = tanhf(o.y);
        int ww = lww[l], hh = lhh[l];
        float locx = fminf(fmaxf(anchors[h][0] + offx * (OFF_SCALE / (float)ww), 0.f), 1.f);
        float locy = fminf(fmaxf(anchors[h][1] + offy * (OFF_SCALE / (float)hh), 0.f), 1.f);
        float xx = locx * (float)ww - 0.5f;
        float yy = locy * (float)hh - 0.5f;
        float x0f = floorf(xx), y0f = floorf(yy);
        int x0 = (int)x0f, y0 = (int)y0f;
        float wx = xx - x0f, wy = yy - y0f;
        float wa = attn_s[e];

        float bx0 = (x0 >= 0)      ? 1.f : 0.f;
        float bx1 = (x0 < ww - 1)  ? 1.f : 0.f;
        float by0 = (y0 >= 0)      ? 1.f : 0.f;
        float by1 = (y0 < hh - 1)  ? 1.f : 0.f;
        int xc0 = max(x0, 0), xc1 = min(x0 + 1, ww - 1);
        int yc0 = max(y0, 0), yc1 = min(y0 + 1, hh - 1);
        unsigned int i00 = (unsigned int)(lst[l] + yc0 * ww + xc0);
        unsigned int i10 = (unsigned int)(lst[l] + yc0 * ww + xc1);
        unsigned int i01 = (unsigned int)(lst[l] + yc1 * ww + xc0);
        unsigned int i11 = (unsigned int)(lst[l] + yc1 * ww + xc1);

        float4 w;
        w.x = wa * (1.f - wx) * (1.f - wy) * bx0 * by0;
        w.y = wa * wx * (1.f - wy) * bx1 * by0;
        w.z = wa * (1.f - wx) * wy * bx0 * by1;
        w.w = wa * wx * wy * bx1 * by1;

        sidx[e][0] = i00 | (i10 << 16);
        sidx[e][1] = i01 | (i11 << 16);
        wcor[e] = w;
    }
    __syncthreads();

    // ---- Phase C: gather bf16 values + accumulate, write bf16 ----
    const int h = tid >> 5;
    const int c = tid & 31;
    const unsigned short* vb = values + (size_t)b * TOTAL * 256 + h * 32 + c;
    float acc = 0.f;
    #pragma unroll 4
    for (int i = 0; i < 80; ++i) {
        int e = h * 80 + i;
        unsigned int p0 = sidx[e][0];
        unsigned int p1 = sidx[e][1];
        float4 w = wcor[e];
        float v00 = bf16_to_f32(vb[(size_t)(p0 & 0xffffu) * 256]);
        float v10 = bf16_to_f32(vb[(size_t)(p0 >> 16) * 256]);
        float v01 = bf16_to_f32(vb[(size_t)(p1 & 0xffffu) * 256]);
        float v11 = bf16_to_f32(vb[(size_t)(p1 >> 16) * 256]);
        acc += w.x * v00 + w.y * v10 + w.z * v01 + w.w * v11;
    }
    out[(size_t)row * 256 + h * 32 + c] = f32_to_bf16_rne(acc);
}

// ---------------------------------------------------------------------------
extern "C" void kernel_launch(void* const* d_in, const int* in_sizes, int n_in,
                              void* d_out, int out_size, void* d_ws, size_t ws_size,
                              hipStream_t stream)
{
    const float* x        = (const float*)d_in[0];
    const float* enc      = (const float*)d_in[1];
    const float* v_w      = (const float*)d_in[2];
    const float* out_w    = (const float*)d_in[3];
    const float* off_w    = (const float*)d_in[4];
    const float* off_b    = (const float*)d_in[5];
    const float* attn_w   = (const float*)d_in[6];
    const float* attn_b   = (const float*)d_in[7];
    const float* ref_w    = (const float*)d_in[8];
    const float* ref_b    = (const float*)d_in[9];
    const float* def_refs = (const float*)d_in[10];
    float* out = (float*)d_out;

    const int M_Q    = BATCH * SEQ;       // 4096
    const int N_OFF  = NH * NL * NP * 2;  // 1280
    const int N_ATTN = NH * NL * NP;      // 640

    // ---- workspace layout (~76.2 MB, no aliasing) ----
    // values_bf16 41.36 | proj_q 31.46 | attn_out_bf16 2.10 |
    // offw 0.655 | attnw 0.328 (adjacent -> merged 1920x256 W) | vw 0.13 | outw 0.13
    char* wsb = (char*)d_ws;
    unsigned short* values_bf16 = (unsigned short*)wsb;
    float* proj_q = (float*)(wsb + (size_t)M_ENC * KDIM * 2);
    unsigned short* attn_out_bf16 = (unsigned short*)((char*)proj_q + (size_t)M_Q * N_Q * 4);
    unsigned short* offw_bf16  = attn_out_bf16 + (size_t)M_Q * EDIM;
    unsigned short* attnw_bf16 = offw_bf16  + (size_t)N_OFF * KDIM;   // contiguous after offw
    unsigned short* vw_bf16    = attnw_bf16 + (size_t)N_ATTN * KDIM;
    unsigned short* outw_bf16  = vw_bf16    + (size_t)EDIM * KDIM;

    dim3 blk(256);

    // 1) all weight casts (offw+attnw land contiguous = merged 1920x256)
    cast4_kernel<<<dim3(304), blk, 0, stream>>>(
        v_w, vw_bf16, (long)EDIM * KDIM,
        off_w, offw_bf16, (long)N_OFF * KDIM,
        attn_w, attnw_bf16, (long)N_ATTN * KDIM,
        out_w, outw_bf16, (long)EDIM * KDIM);

    // 2) values = enc @ v_w^T (fused-cast MFMA, bf16 out)
    gemm_f32a_bf16out_kernel<<<dim3((M_ENC + 127) / 128, EDIM / 128), blk, 0, stream>>>(
        enc, vw_bf16, values_bf16, M_ENC, EDIM);

    // 3) merged query projection: [off|attn] = x @ [off_w;attn_w]^T + bias
    gemm_f32a_f32out_kernel<<<dim3(M_Q / 128, N_Q / 128), blk, 0, stream>>>(
        x, offw_bf16, off_b, attn_b, N_OFF, proj_q, M_Q, N_Q);

    // 4) deformable sampling (ref-proj fused, parallel; bf16 in/out)
    deform_sample_kernel<<<dim3(M_Q), blk, 0, stream>>>(
        values_bf16, x, ref_w, ref_b, proj_q, def_refs, attn_out_bf16);

    // 5) out = attn_out @ out_w^T (bf16-A MFMA, f32 out)
    gemm_bf16a_kernel<<<dim3(M_Q / 128, EDIM / 128), blk, 0, stream>>>(
        attn_out_bf16, outw_bf16, out, M_Q, EDIM);
}

// Round 12
// 275.274 us; speedup vs baseline: 1.2155x; 1.0639x over previous
//
#include <hip/hip_runtime.h>
#include <hip/hip_bf16.h>
#include <math.h>

#define NH 8
#define HD 32
#define EDIM 256
#define NL 4
#define NP 20
#define NR 4
#define SEQ 1024
#define BATCH 4
#define TOTAL 20197
#define OFF_SCALE 4.0f

#define M_ENC (BATCH * TOTAL)   // 80788
#define KDIM 256
#define LDSW 40                 // padded LDS row stride (bf16): 80B
#define N_Q 1920                // merged projection width: off(1280) + attn(640)

typedef short bf16x8 __attribute__((ext_vector_type(8)));
typedef float f32x4  __attribute__((ext_vector_type(4)));

__device__ __forceinline__ unsigned short f32_to_bf16_rne(float f) {
    unsigned u = __float_as_uint(f);
    return (unsigned short)((u + 0x7fffu + ((u >> 16) & 1u)) >> 16);
}
__device__ __forceinline__ float fast_tanh(float x) {
    x = fminf(fmaxf(x, -10.f), 10.f);
    float t = __expf(2.f * x);
    return (t - 1.f) * __frcp_rn(t + 1.f);
}

// ---------------------------------------------------------------------------
// Quad f32 -> bf16 weight cast (RNE), one dispatch. Sizes divisible by 8.
// ---------------------------------------------------------------------------
__global__ __launch_bounds__(256) void cast4_kernel(
    const float* __restrict__ s0, unsigned short* __restrict__ d0, long n0,
    const float* __restrict__ s1, unsigned short* __restrict__ d1, long n1,
    const float* __restrict__ s2, unsigned short* __restrict__ d2, long n2,
    const float* __restrict__ s3, unsigned short* __restrict__ d3, long n3)
{
    long c0 = n0 >> 3, c1 = n1 >> 3, c2 = n2 >> 3, c3 = n3 >> 3;
    long total = c0 + c1 + c2 + c3;
    long gid = (long)blockIdx.x * blockDim.x + threadIdx.x;
    long stride = (long)gridDim.x * blockDim.x;
    for (long i = gid; i < total; i += stride) {
        const float* s; unsigned short* d; long e;
        if (i < c0)                 { s = s0; d = d0; e = i * 8; }
        else if (i < c0 + c1)       { s = s1; d = d1; e = (i - c0) * 8; }
        else if (i < c0 + c1 + c2)  { s = s2; d = d2; e = (i - c0 - c1) * 8; }
        else                        { s = s3; d = d3; e = (i - c0 - c1 - c2) * 8; }
        float4 a = *reinterpret_cast<const float4*>(s + e);
        float4 b = *reinterpret_cast<const float4*>(s + e + 4);
        float f[8] = {a.x, a.y, a.z, a.w, b.x, b.y, b.z, b.w};
        unsigned short o[8];
        #pragma unroll
        for (int j = 0; j < 8; ++j) o[j] = f32_to_bf16_rne(f[j]);
        *reinterpret_cast<uint4*>(d + e) = *reinterpret_cast<const uint4*>(o);
    }
}

// ---------------------------------------------------------------------------
// Fused-cast f32-A MFMA GEMM, f32 out, split bias:
//   C[m][n] = sum_k bf16(A_f32[m][k]) * W_bf16[n][k] + bias(n)
// ---------------------------------------------------------------------------
__global__ __launch_bounds__(256) void gemm_f32a_f32out_kernel(
    const float* __restrict__ A,
    const unsigned short* __restrict__ W,
    const float* __restrict__ b0, const float* __restrict__ b1, int bsplit,
    float* __restrict__ C,
    int M_real, int N)
{
    __shared__ __align__(16) unsigned short As[128 * LDSW];
    __shared__ __align__(16) unsigned short Ws[128 * LDSW];

    const int tid  = threadIdx.x;
    const int m0   = blockIdx.x * 128;
    const int n0   = blockIdx.y * 128;
    const int wave = tid >> 6;
    const int lane = tid & 63;
    const int wr   = wave >> 1;
    const int wc   = wave & 1;
    const int lrow = lane & 15;
    const int kg   = lane >> 4;

    f32x4 acc[4][4] = {};

    for (int k0 = 0; k0 < KDIM; k0 += 32) {
        #pragma unroll
        for (int p = 0; p < 4; ++p) {
            int s   = tid + p * 256;
            int row = s >> 3;
            int sl  = s & 7;
            int gm  = m0 + row;
            float4 v = make_float4(0.f, 0.f, 0.f, 0.f);
            if (gm < M_real)
                v = *reinterpret_cast<const float4*>(&A[(size_t)gm * KDIM + k0 + sl * 4]);
            unsigned short o[4] = {
                f32_to_bf16_rne(v.x), f32_to_bf16_rne(v.y),
                f32_to_bf16_rne(v.z), f32_to_bf16_rne(v.w)};
            *reinterpret_cast<uint2*>(&As[row * LDSW + sl * 4]) =
                *reinterpret_cast<const uint2*>(o);
        }
        #pragma unroll
        for (int it = 0; it < 2; ++it) {
            int s   = tid + it * 256;
            int row = s >> 2;
            int ks  = s & 3;
            uint4 vw = *reinterpret_cast<const uint4*>(
                W + (size_t)(n0 + row) * KDIM + k0 + ks * 8);
            *reinterpret_cast<uint4*>(&Ws[row * LDSW + ks * 8]) = vw;
        }
        __syncthreads();

        bf16x8 af[4], bfr[4];
        #pragma unroll
        for (int mi = 0; mi < 4; ++mi)
            af[mi] = *reinterpret_cast<const bf16x8*>(
                &As[(wr * 64 + mi * 16 + lrow) * LDSW + kg * 8]);
        #pragma unroll
        for (int nj = 0; nj < 4; ++nj)
            bfr[nj] = *reinterpret_cast<const bf16x8*>(
                &Ws[(wc * 64 + nj * 16 + lrow) * LDSW + kg * 8]);
        #pragma unroll
        for (int mi = 0; mi < 4; ++mi)
            #pragma unroll
            for (int nj = 0; nj < 4; ++nj)
                acc[mi][nj] = __builtin_amdgcn_mfma_f32_16x16x32_bf16(
                    af[mi], bfr[nj], acc[mi][nj], 0, 0, 0);
        __syncthreads();
    }

    #pragma unroll
    for (int mi = 0; mi < 4; ++mi) {
        #pragma unroll
        for (int nj = 0; nj < 4; ++nj) {
            int row_base = m0 + wr * 64 + mi * 16 + kg * 4;
            int col      = n0 + wc * 64 + nj * 16 + lrow;
            float bv = 0.f;
            if (b0) bv = (col < bsplit) ? b0[col] : b1[col - bsplit];
            #pragma unroll
            for (int r = 0; r < 4; ++r) {
                int row = row_base + r;
                if (row < M_real)
                    C[(size_t)row * N + col] = acc[mi][nj][r] + bv;
            }
        }
    }
}

// ---------------------------------------------------------------------------
// Fused-cast f32-A MFMA GEMM, bf16 out, no bias (values GEMM).
// ---------------------------------------------------------------------------
__global__ __launch_bounds__(256) void gemm_f32a_bf16out_kernel(
    const float* __restrict__ A,
    const unsigned short* __restrict__ W,
    unsigned short* __restrict__ C,
    int M_real, int N)
{
    __shared__ __align__(16) unsigned short As[128 * LDSW];
    __shared__ __align__(16) unsigned short Ws[128 * LDSW];

    const int tid  = threadIdx.x;
    const int m0   = blockIdx.x * 128;
    const int n0   = blockIdx.y * 128;
    const int wave = tid >> 6;
    const int lane = tid & 63;
    const int wr   = wave >> 1;
    const int wc   = wave & 1;
    const int lrow = lane & 15;
    const int kg   = lane >> 4;

    f32x4 acc[4][4] = {};

    for (int k0 = 0; k0 < KDIM; k0 += 32) {
        #pragma unroll
        for (int p = 0; p < 4; ++p) {
            int s   = tid + p * 256;
            int row = s >> 3;
            int sl  = s & 7;
            int gm  = m0 + row;
            float4 v = make_float4(0.f, 0.f, 0.f, 0.f);
            if (gm < M_real)
                v = *reinterpret_cast<const float4*>(&A[(size_t)gm * KDIM + k0 + sl * 4]);
            unsigned short o[4] = {
                f32_to_bf16_rne(v.x), f32_to_bf16_rne(v.y),
                f32_to_bf16_rne(v.z), f32_to_bf16_rne(v.w)};
            *reinterpret_cast<uint2*>(&As[row * LDSW + sl * 4]) =
                *reinterpret_cast<const uint2*>(o);
        }
        #pragma unroll
        for (int it = 0; it < 2; ++it) {
            int s   = tid + it * 256;
            int row = s >> 2;
            int ks  = s & 3;
            uint4 vw = *reinterpret_cast<const uint4*>(
                W + (size_t)(n0 + row) * KDIM + k0 + ks * 8);
            *reinterpret_cast<uint4*>(&Ws[row * LDSW + ks * 8]) = vw;
        }
        __syncthreads();

        bf16x8 af[4], bfr[4];
        #pragma unroll
        for (int mi = 0; mi < 4; ++mi)
            af[mi] = *reinterpret_cast<const bf16x8*>(
                &As[(wr * 64 + mi * 16 + lrow) * LDSW + kg * 8]);
        #pragma unroll
        for (int nj = 0; nj < 4; ++nj)
            bfr[nj] = *reinterpret_cast<const bf16x8*>(
                &Ws[(wc * 64 + nj * 16 + lrow) * LDSW + kg * 8]);
        #pragma unroll
        for (int mi = 0; mi < 4; ++mi)
            #pragma unroll
            for (int nj = 0; nj < 4; ++nj)
                acc[mi][nj] = __builtin_amdgcn_mfma_f32_16x16x32_bf16(
                    af[mi], bfr[nj], acc[mi][nj], 0, 0, 0);
        __syncthreads();
    }

    #pragma unroll
    for (int mi = 0; mi < 4; ++mi) {
        #pragma unroll
        for (int nj = 0; nj < 4; ++nj) {
            int row_base = m0 + wr * 64 + mi * 16 + kg * 4;
            int col      = n0 + wc * 64 + nj * 16 + lrow;
            #pragma unroll
            for (int r = 0; r < 4; ++r) {
                int row = row_base + r;
                if (row < M_real)
                    C[(size_t)row * N + col] = f32_to_bf16_rne(acc[mi][nj][r]);
            }
        }
    }
}

// ---------------------------------------------------------------------------
// bf16-A MFMA GEMM, f32 out (out projection).
// ---------------------------------------------------------------------------
__global__ __launch_bounds__(256) void gemm_bf16a_kernel(
    const unsigned short* __restrict__ A,
    const unsigned short* __restrict__ W,
    float* __restrict__ C,
    int M_real, int N)
{
    __shared__ __align__(16) unsigned short As[128 * LDSW];
    __shared__ __align__(16) unsigned short Ws[128 * LDSW];

    const int tid  = threadIdx.x;
    const int m0   = blockIdx.x * 128;
    const int n0   = blockIdx.y * 128;
    const int wave = tid >> 6;
    const int lane = tid & 63;
    const int wr   = wave >> 1;
    const int wc   = wave & 1;
    const int lrow = lane & 15;
    const int kg   = lane >> 4;

    f32x4 acc[4][4] = {};

    for (int k0 = 0; k0 < KDIM; k0 += 32) {
        #pragma unroll
        for (int it = 0; it < 2; ++it) {
            int s   = tid + it * 256;
            int row = s >> 2;
            int ks  = s & 3;
            int gm  = m0 + row;
            uint4 va = make_uint4(0u, 0u, 0u, 0u);
            if (gm < M_real)
                va = *reinterpret_cast<const uint4*>(
                    A + (size_t)gm * KDIM + k0 + ks * 8);
            uint4 vw = *reinterpret_cast<const uint4*>(
                W + (size_t)(n0 + row) * KDIM + k0 + ks * 8);
            *reinterpret_cast<uint4*>(&As[row * LDSW + ks * 8]) = va;
            *reinterpret_cast<uint4*>(&Ws[row * LDSW + ks * 8]) = vw;
        }
        __syncthreads();

        bf16x8 af[4], bfr[4];
        #pragma unroll
        for (int mi = 0; mi < 4; ++mi)
            af[mi] = *reinterpret_cast<const bf16x8*>(
                &As[(wr * 64 + mi * 16 + lrow) * LDSW + kg * 8]);
        #pragma unroll
        for (int nj = 0; nj < 4; ++nj)
            bfr[nj] = *reinterpret_cast<const bf16x8*>(
                &Ws[(wc * 64 + nj * 16 + lrow) * LDSW + kg * 8]);
        #pragma unroll
        for (int mi = 0; mi < 4; ++mi)
            #pragma unroll
            for (int nj = 0; nj < 4; ++nj)
                acc[mi][nj] = __builtin_amdgcn_mfma_f32_16x16x32_bf16(
                    af[mi], bfr[nj], acc[mi][nj], 0, 0, 0);
        __syncthreads();
    }

    #pragma unroll
    for (int mi = 0; mi < 4; ++mi) {
        #pragma unroll
        for (int nj = 0; nj < 4; ++nj) {
            int row_base = m0 + wr * 64 + mi * 16 + kg * 4;
            int col      = n0 + wc * 64 + nj * 16 + lrow;
            #pragma unroll
            for (int r = 0; r < 4; ++r) {
                int row = row_base + r;
                if (row < M_real)
                    C[(size_t)row * N + col] = acc[mi][nj][r];
            }
        }
    }
}

// ---------------------------------------------------------------------------
// Deformable sampling. One block per query row, 256 threads.
//  Phase A : tid<64: ref dots (2 threads/output, shfl reduce);
//            tid>=96: vector-load attn logits.
//  Phase A2: tid<8 anchors; all: per-head softmax via shfl_xor.
//  Phase B : 640 samples -> u16-packed corner indices + attn-folded weights
//            (fast tanh via __expf).
//  Phase C : PAIRED-CHANNEL gathers: lane (h, sub, c2) loads u32 = 2 bf16
//            channels per corner; sub-groups split samples 40/40; shfl-xor(16)
//            combine; packed u32 bf16-pair store. 160 loads/lane (was 320).
// ---------------------------------------------------------------------------
__global__ __launch_bounds__(256) void deform_sample_kernel(
    const unsigned short* __restrict__ values, // (B, TOTAL, 256) bf16
    const float* __restrict__ x,          // (B*SEQ, 256)
    const float* __restrict__ ref_w,      // (32, 256)
    const float* __restrict__ ref_b,      // (32,)
    const float* __restrict__ proj_q,     // (B*SEQ, 1920): off[0:1280] attn[1280:1920]
    const float* __restrict__ def_refs,   // (NR, 2)
    unsigned short* __restrict__ out)     // (B*SEQ, 256) bf16
{
    const int row = blockIdx.x;
    const int b   = row >> 10;           // SEQ = 1024
    const int tid = threadIdx.x;

    __shared__ float  attn_s[NH * NL * NP];          // 640 f32
    __shared__ float  anchors[NH][2];
    __shared__ float  refv[NH * NR];                 // 32
    __shared__ unsigned int sidx[NH * NL * NP][2];   // 4 x u16 packed
    __shared__ float4 wcor[NH * NL * NP];

    const float* prow = proj_q + (size_t)row * N_Q;

    // ---- Phase A ----
    if (tid >= 96) {            // 160 threads: attn logits (cols 1280..1919)
        int i = tid - 96;
        reinterpret_cast<float4*>(attn_s)[i] =
            reinterpret_cast<const float4*>(prow + 1280)[i];
    } else if (tid < 64) {      // wave 0: ref dots, 2 threads per output
        const int r    = tid >> 1;
        const int half = tid & 1;
        const float* xr = x + (size_t)row * 256 + half * 128;
        const float* wr = ref_w + (size_t)r * 256 + half * 128;
        float dot = 0.f;
        #pragma unroll
        for (int k = 0; k < 128; k += 4) {
            float4 xv = *reinterpret_cast<const float4*>(xr + k);
            float4 wv = *reinterpret_cast<const float4*>(wr + k);
            dot += xv.x * wv.x; dot += xv.y * wv.y;
            dot += xv.z * wv.z; dot += xv.w * wv.w;
        }
        dot += __shfl_xor(dot, 1, 64);
        if (half == 0) refv[r] = dot + ref_b[r];
    }
    __syncthreads();

    // ---- Phase A2: anchors (tid<8) + per-head softmax over 80 ----
    if (tid < NH) {
        const int h = tid;
        float rv[NR];
        float rmax = -1e30f;
        #pragma unroll
        for (int r = 0; r < NR; ++r) {
            rv[r] = refv[h * NR + r];
            rmax = fmaxf(rmax, rv[r]);
        }
        float rsum = 0.f;
        #pragma unroll
        for (int r = 0; r < NR; ++r) { rv[r] = __expf(rv[r] - rmax); rsum += rv[r]; }
        float ax = 0.f, ay = 0.f;
        #pragma unroll
        for (int r = 0; r < NR; ++r) {
            float pr = rv[r] / rsum;
            float sx = 1.f / (1.f + __expf(-def_refs[r * 2 + 0]));
            float sy = 1.f / (1.f + __expf(-def_refs[r * 2 + 1]));
            ax += pr * sx; ay += pr * sy;
        }
        anchors[h][0] = ax; anchors[h][1] = ay;
    }
    {
        const int g = tid >> 5;   // head
        const int l = tid & 31;
        float v0 = attn_s[g * 80 + l];
        float v1 = attn_s[g * 80 + 32 + l];
        float v2 = (l < 16) ? attn_s[g * 80 + 64 + l] : -1e30f;
        float m = fmaxf(fmaxf(v0, v1), v2);
        #pragma unroll
        for (int d = 16; d >= 1; d >>= 1) m = fmaxf(m, __shfl_xor(m, d, 64));
        float e0 = __expf(v0 - m), e1 = __expf(v1 - m);
        float e2 = (l < 16) ? __expf(v2 - m) : 0.f;
        float s = e0 + e1 + e2;
        #pragma unroll
        for (int d = 16; d >= 1; d >>= 1) s += __shfl_xor(s, d, 64);
        float inv = 1.f / s;
        __syncthreads();   // all reads of raw logits done before overwrite
        attn_s[g * 80 + l]      = e0 * inv;
        attn_s[g * 80 + 32 + l] = e1 * inv;
        if (l < 16) attn_s[g * 80 + 64 + l] = e2 * inv;
    }
    __syncthreads();

    // ---- Phase B: locations -> packed u16 indices + folded weights ----
    const int lhh[NL] = {100, 50, 25, 13};
    const int lww[NL] = {152, 76, 38, 19};
    const int lst[NL] = {0, 15200, 19000, 19950};

    for (int e = tid; e < NH * NL * NP; e += 256) {
        int h = e / 80;
        int rem = e - h * 80;
        int l = rem / 20;
        const float2 o = *reinterpret_cast<const float2*>(prow + e * 2);
        float offx = fast_tanh(o.x);
        float offy = fast_tanh(o.y);
        int ww = lww[l], hh = lhh[l];
        float locx = fminf(fmaxf(anchors[h][0] + offx * (OFF_SCALE / (float)ww), 0.f), 1.f);
        float locy = fminf(fmaxf(anchors[h][1] + offy * (OFF_SCALE / (float)hh), 0.f), 1.f);
        float xx = locx * (float)ww - 0.5f;
        float yy = locy * (float)hh - 0.5f;
        float x0f = floorf(xx), y0f = floorf(yy);
        int x0 = (int)x0f, y0 = (int)y0f;
        float wx = xx - x0f, wy = yy - y0f;
        float wa = attn_s[e];

        float bx0 = (x0 >= 0)      ? 1.f : 0.f;
        float bx1 = (x0 < ww - 1)  ? 1.f : 0.f;
        float by0 = (y0 >= 0)      ? 1.f : 0.f;
        float by1 = (y0 < hh - 1)  ? 1.f : 0.f;
        int xc0 = max(x0, 0), xc1 = min(x0 + 1, ww - 1);
        int yc0 = max(y0, 0), yc1 = min(y0 + 1, hh - 1);
        unsigned int i00 = (unsigned int)(lst[l] + yc0 * ww + xc0);
        unsigned int i10 = (unsigned int)(lst[l] + yc0 * ww + xc1);
        unsigned int i01 = (unsigned int)(lst[l] + yc1 * ww + xc0);
        unsigned int i11 = (unsigned int)(lst[l] + yc1 * ww + xc1);

        float4 w;
        w.x = wa * (1.f - wx) * (1.f - wy) * bx0 * by0;
        w.y = wa * wx * (1.f - wy) * bx1 * by0;
        w.z = wa * (1.f - wx) * wy * bx0 * by1;
        w.w = wa * wx * wy * bx1 * by1;

        sidx[e][0] = i00 | (i10 << 16);
        sidx[e][1] = i01 | (i11 << 16);
        wcor[e] = w;
    }
    __syncthreads();

    // ---- Phase C: paired-channel u32 gathers, sample-split, shfl combine ----
    const int h   = tid >> 5;         // head
    const int l   = tid & 31;
    const int sub = l >> 4;           // sample half: 0 -> [0,40), 1 -> [40,80)
    const int c2  = l & 15;           // channel pair: channels 2*c2, 2*c2+1
    // values row = 256 bf16 = 128 u32; head h at u32 index h*16 + c2
    const unsigned int* vbu =
        reinterpret_cast<const unsigned int*>(values + (size_t)b * TOTAL * 256)
        + h * 16 + c2;
    float accL = 0.f, accH = 0.f;
    #pragma unroll 4
    for (int i = 0; i < 40; ++i) {
        int e = h * 80 + sub * 40 + i;
        unsigned int p0 = sidx[e][0];
        unsigned int p1 = sidx[e][1];
        float4 w = wcor[e];
        unsigned int u00 = vbu[(size_t)(p0 & 0xffffu) * 128];
        unsigned int u10 = vbu[(size_t)(p0 >> 16) * 128];
        unsigned int u01 = vbu[(size_t)(p1 & 0xffffu) * 128];
        unsigned int u11 = vbu[(size_t)(p1 >> 16) * 128];
        accL += w.x * __uint_as_float(u00 << 16);
        accH += w.x * __uint_as_float(u00 & 0xffff0000u);
        accL += w.y * __uint_as_float(u10 << 16);
        accH += w.y * __uint_as_float(u10 & 0xffff0000u);
        accL += w.z * __uint_as_float(u01 << 16);
        accH += w.z * __uint_as_float(u01 & 0xffff0000u);
        accL += w.w * __uint_as_float(u11 << 16);
        accH += w.w * __uint_as_float(u11 & 0xffff0000u);
    }
    accL += __shfl_xor(accL, 16, 64);   // combine the two sample halves
    accH += __shfl_xor(accH, 16, 64);
    if (sub == 0) {
        unsigned int packed = (unsigned int)f32_to_bf16_rne(accL)
                            | ((unsigned int)f32_to_bf16_rne(accH) << 16);
        reinterpret_cast<unsigned int*>(out)[(size_t)row * 128 + h * 16 + c2] = packed;
    }
}

// ---------------------------------------------------------------------------
extern "C" void kernel_launch(void* const* d_in, const int* in_sizes, int n_in,
                              void* d_out, int out_size, void* d_ws, size_t ws_size,
                              hipStream_t stream)
{
    const float* x        = (const float*)d_in[0];
    const float* enc      = (const float*)d_in[1];
    const float* v_w      = (const float*)d_in[2];
    const float* out_w    = (const float*)d_in[3];
    const float* off_w    = (const float*)d_in[4];
    const float* off_b    = (const float*)d_in[5];
    const float* attn_w   = (const float*)d_in[6];
    const float* attn_b   = (const float*)d_in[7];
    const float* ref_w    = (const float*)d_in[8];
    const float* ref_b    = (const float*)d_in[9];
    const float* def_refs = (const float*)d_in[10];
    float* out = (float*)d_out;

    const int M_Q    = BATCH * SEQ;       // 4096
    const int N_OFF  = NH * NL * NP * 2;  // 1280
    const int N_ATTN = NH * NL * NP;      // 640

    // ---- workspace layout (~76.2 MB, no aliasing) ----
    char* wsb = (char*)d_ws;
    unsigned short* values_bf16 = (unsigned short*)wsb;
    float* proj_q = (float*)(wsb + (size_t)M_ENC * KDIM * 2);
    unsigned short* attn_out_bf16 = (unsigned short*)((char*)proj_q + (size_t)M_Q * N_Q * 4);
    unsigned short* offw_bf16  = attn_out_bf16 + (size_t)M_Q * EDIM;
    unsigned short* attnw_bf16 = offw_bf16  + (size_t)N_OFF * KDIM;   // contiguous after offw
    unsigned short* vw_bf16    = attnw_bf16 + (size_t)N_ATTN * KDIM;
    unsigned short* outw_bf16  = vw_bf16    + (size_t)EDIM * KDIM;

    dim3 blk(256);

    // 1) all weight casts (offw+attnw land contiguous = merged 1920x256)
    cast4_kernel<<<dim3(304), blk, 0, stream>>>(
        v_w, vw_bf16, (long)EDIM * KDIM,
        off_w, offw_bf16, (long)N_OFF * KDIM,
        attn_w, attnw_bf16, (long)N_ATTN * KDIM,
        out_w, outw_bf16, (long)EDIM * KDIM);

    // 2) values = enc @ v_w^T (fused-cast MFMA, bf16 out)
    gemm_f32a_bf16out_kernel<<<dim3((M_ENC + 127) / 128, EDIM / 128), blk, 0, stream>>>(
        enc, vw_bf16, values_bf16, M_ENC, EDIM);

    // 3) merged query projection: [off|attn] = x @ [off_w;attn_w]^T + bias
    gemm_f32a_f32out_kernel<<<dim3(M_Q / 128, N_Q / 128), blk, 0, stream>>>(
        x, offw_bf16, off_b, attn_b, N_OFF, proj_q, M_Q, N_Q);

    // 4) deformable sampling (ref-proj fused; paired-channel gathers)
    deform_sample_kernel<<<dim3(M_Q), blk, 0, stream>>>(
        values_bf16, x, ref_w, ref_b, proj_q, def_refs, attn_out_bf16);

    // 5) out = attn_out @ out_w^T (bf16-A MFMA, f32 out)
    gemm_bf16a_kernel<<<dim3(M_Q / 128, EDIM / 128), blk, 0, stream>>>(
        attn_out_bf16, outw_bf16, out, M_Q, EDIM);
}